// Round 1
// baseline (222.183 us; speedup 1.0000x reference)
//
#include <hip/hip_runtime.h>
#include <hip/hip_bf16.h>
#include <math.h>

#define S_LEN 2048
#define HDIM  2048
#define N_H   16
#define N_KV  2
#define HD_   128
#define NQKV  2560

typedef __attribute__((ext_vector_type(8))) short bf16x8;
typedef __attribute__((ext_vector_type(4))) float f32x4;

#define GLDS16(gsrc, ldst)                                                      \
  __builtin_amdgcn_global_load_lds(                                             \
      (const __attribute__((address_space(1))) void*)(gsrc),                    \
      (__attribute__((address_space(3))) void*)(ldst), 16, 0, 0)

__device__ __forceinline__ ushort f2b(float x) {
  union { __hip_bfloat16 b; ushort u; } c;
  c.b = __float2bfloat16(x);
  return c.u;
}
__device__ __forceinline__ float b2f(ushort u) {
  union { float f; unsigned v; } c;
  c.v = ((unsigned)u) << 16;
  return c.f;
}

// ---------------- f32 -> bf16 elementwise (x conversion) ----------------
__global__ __launch_bounds__(256) void k_f32_to_bf16(const float* __restrict__ src,
                                                     ushort* __restrict__ dst, int n4) {
  int i = blockIdx.x * 256 + threadIdx.x;
  if (i >= n4) return;
  float4 v = ((const float4*)src)[i];
  ushort4 o;
  o.x = f2b(v.x); o.y = f2b(v.y); o.z = f2b(v.z); o.w = f2b(v.w);
  ((ushort4*)dst)[i] = o;
}

// ---------------- f32 [R][C] -> bf16 [C][R] tiled transpose ----------------
__global__ __launch_bounds__(256) void k_transpose_bf16(const float* __restrict__ src,
                                                        ushort* __restrict__ dst,
                                                        int R, int C) {
  __shared__ float t[64][65];
  int c0 = blockIdx.x * 64, r0 = blockIdx.y * 64;
  int tx = threadIdx.x & 63, ty = threadIdx.x >> 6;
#pragma unroll
  for (int i = 0; i < 16; ++i)
    t[i * 4 + ty][tx] = src[(size_t)(r0 + i * 4 + ty) * C + (c0 + tx)];
  __syncthreads();
#pragma unroll
  for (int i = 0; i < 16; ++i)
    dst[(size_t)(c0 + i * 4 + ty) * R + (r0 + tx)] = f2b(t[tx][i * 4 + ty]);
}

// ---------------- bf16 GEMM: C[M][N] = A[M][K] * Bt[N][K]^T ----------------
// OUT_MODE 0: bf16 out + bias (QKV);  OUT_MODE 1: f32 out, bf16-rounded (Wo)
template <int OUT_MODE>
__global__ __launch_bounds__(256) void k_gemm_bt(const ushort* __restrict__ A,
                                                 const ushort* __restrict__ Bt,
                                                 void* __restrict__ Cp,
                                                 const float* __restrict__ bq,
                                                 const float* __restrict__ bk,
                                                 const float* __restrict__ bv,
                                                 int M, int N, int K) {
  __shared__ ushort lA[128 * 32];
  __shared__ ushort lB[128 * 32];
  const int tid = threadIdx.x;
  const int w = tid >> 6, lane = tid & 63;
  const int lr = lane & 15, lg = lane >> 4;
  const int bm = blockIdx.x * 128, bn = blockIdx.y * 128;
  const int wm = (w >> 1) * 64, wn = (w & 1) * 64;
  f32x4 acc[4][4] = {};

  for (int k0 = 0; k0 < K; k0 += 32) {
    __syncthreads();
#pragma unroll
    for (int it = 0; it < 2; ++it) {
      const int idx = it * 256 + tid;
      const int row = idx >> 2;
      const int kc = (idx & 3) * 8;
      GLDS16(A + (size_t)(bm + row) * K + k0 + kc, lA + (it * 4 + w) * 512);
      GLDS16(Bt + (size_t)(bn + row) * K + k0 + kc, lB + (it * 4 + w) * 512);
    }
    __syncthreads();
    bf16x8 af[4], bf[4];
#pragma unroll
    for (int i = 0; i < 4; ++i) {
      af[i] = *(const bf16x8*)(lA + (wm + i * 16 + lr) * 32 + lg * 8);
      bf[i] = *(const bf16x8*)(lB + (wn + i * 16 + lr) * 32 + lg * 8);
    }
#pragma unroll
    for (int mi = 0; mi < 4; ++mi)
#pragma unroll
      for (int ni = 0; ni < 4; ++ni)
        acc[mi][ni] =
            __builtin_amdgcn_mfma_f32_16x16x32_bf16(af[mi], bf[ni], acc[mi][ni], 0, 0, 0);
  }

#pragma unroll
  for (int mi = 0; mi < 4; ++mi)
#pragma unroll
    for (int ni = 0; ni < 4; ++ni)
#pragma unroll
      for (int r = 0; r < 4; ++r) {
        const int row = bm + wm + mi * 16 + lg * 4 + r;
        const int col = bn + wn + ni * 16 + lr;
        const float v = acc[mi][ni][r];
        if (OUT_MODE == 0) {
          float bias = (col < 2048) ? bq[col] : (col < 2304 ? bk[col - 2048] : bv[col - 2304]);
          float vb = b2f(f2b(v)) + b2f(f2b(bias));  // bf16 add semantics
          ((ushort*)Cp)[(size_t)row * N + col] = f2b(vb);
        } else {
          ((float*)Cp)[(size_t)row * N + col] = b2f(f2b(v));  // ref rounds to bf16
        }
      }
}

// ---------------- RoPE + cache writes + V transpose ----------------
__global__ __launch_bounds__(256) void k_rope(const ushort* __restrict__ qkv,
                                              const int* __restrict__ pos_ids,
                                              ushort* __restrict__ q_r,
                                              ushort* __restrict__ k_r,
                                              ushort* __restrict__ v_t,
                                              float* __restrict__ cache_k,
                                              float* __restrict__ cache_v) {
  const int s = blockIdx.x;
  const int t = threadIdx.x;
  const int i = t & 63, g = t >> 6;
  const float pos = (float)pos_ids[s];
  const float freq = (float)(1.0 / pow(1000000.0, (double)i / 64.0));
  float sn, cs;
  sincosf(pos * freq, &sn, &cs);
  const ushort* row = qkv + (size_t)s * NQKV;

  // Q: heads g, g+4, g+8, g+12 at pair index i
#pragma unroll
  for (int j = 0; j < 4; ++j) {
    const int h = j * 4 + g;
    const float x1 = b2f(row[h * 128 + i]);
    const float x2 = b2f(row[h * 128 + 64 + i]);
    const float o1 = x1 * cs - x2 * sn;
    const float o2 = x1 * sn + x2 * cs;
    const size_t qo = ((size_t)h * S_LEN + s) * 128;
    q_r[qo + i] = f2b(o1);
    q_r[qo + 64 + i] = f2b(o2);
  }
  // K (kv head = g for g<2) — cache_k keeps full f32 precision
  if (g < 2) {
    const int kv = g;
    const float x1 = b2f(row[2048 + kv * 128 + i]);
    const float x2 = b2f(row[2048 + kv * 128 + 64 + i]);
    const float o1 = x1 * cs - x2 * sn;
    const float o2 = x1 * sn + x2 * cs;
    const size_t ko = ((size_t)kv * S_LEN + s) * 128;
    k_r[ko + i] = f2b(o1);
    k_r[ko + 64 + i] = f2b(o2);
    const size_t co = ((size_t)s * 2 + kv) * 128;
    cache_k[co + i] = o1;
    cache_k[co + 64 + i] = o2;
  }
  // V: copy bits to transposed layout + f32 cache
  {
    const int kv = t >> 7, d = t & 127;
    const ushort bits = row[2304 + kv * 128 + d];
    cache_v[((size_t)s * 2 + kv) * 128 + d] = b2f(bits);
    v_t[((size_t)kv * 128 + d) * S_LEN + s] = bits;
  }
}

// ---------------- flash attention (causal, GQA 8:1) ----------------
__global__ __launch_bounds__(256) void k_attn(const ushort* __restrict__ q_r,
                                              const ushort* __restrict__ k_r,
                                              const ushort* __restrict__ v_t,
                                              ushort* __restrict__ attn_b) {
  __shared__ ushort lK[64 * 128];   // [key][d], 16B-slot XOR swizzled by key&7
  __shared__ ushort lV[128 * 64];   // [d][key], 16B-slot XOR swizzled by d&7
  __shared__ ushort lP[4][16 * 72]; // per-wave P tile, padded stride 72
  const int h = blockIdx.y, kvh = h >> 3;
  const int qb = blockIdx.x * 64;
  const int tid = threadIdx.x, w = tid >> 6, lane = tid & 63;
  const int lr = lane & 15, lg = lane >> 4;
  const float scale = 0.08838834764831845f;  // 1/sqrt(128)

  bf16x8 qf[4];
  {
    const size_t qo = ((size_t)h * S_LEN + qb + w * 16 + lr) * 128 + lg * 8;
#pragma unroll
    for (int fd = 0; fd < 4; ++fd) qf[fd] = *(const bf16x8*)(q_r + qo + fd * 32);
  }
  f32x4 o[8];
#pragma unroll
  for (int f = 0; f < 8; ++f) o[f] = (f32x4){0.f, 0.f, 0.f, 0.f};
  float m[4] = {-INFINITY, -INFINITY, -INFINITY, -INFINITY};
  float l[4] = {0.f, 0.f, 0.f, 0.f};

  const int nkt = blockIdx.x + 1;
  for (int kt = 0; kt < nkt; ++kt) {
    const int kb = kt * 64;
    __syncthreads();
#pragma unroll
    for (int it = 0; it < 4; ++it) {
      const int idx = it * 256 + tid;
      {  // K tile: 64 keys x 128 d (pre-swizzled global source, linear LDS dest)
        const int key = idx >> 4, sl = idx & 15;
        const int ss = sl ^ (key & 7);
        GLDS16(k_r + ((size_t)kvh * S_LEN + kb + key) * 128 + ss * 8,
               lK + (it * 4 + w) * 512);
      }
      {  // V tile (transposed): 128 d x 64 keys
        const int d = idx >> 3, sl = idx & 7;
        const int ss = sl ^ (d & 7);
        GLDS16(v_t + ((size_t)kvh * 128 + d) * S_LEN + kb + ss * 8,
               lV + (it * 4 + w) * 512);
      }
    }
    __syncthreads();

    // QK^T: D[q][key], q = lg*4+r, key = kf*16+lr
    f32x4 sf[4];
#pragma unroll
    for (int kf = 0; kf < 4; ++kf) {
      f32x4 a = (f32x4){0.f, 0.f, 0.f, 0.f};
      const int key = kf * 16 + lr;
#pragma unroll
      for (int fd = 0; fd < 4; ++fd) {
        const int sw = (fd * 4 + lg) ^ (key & 7);
        const bf16x8 kf8 = *(const bf16x8*)(lK + key * 128 + sw * 8);
        a = __builtin_amdgcn_mfma_f32_16x16x32_bf16(qf[fd], kf8, a, 0, 0, 0);
      }
      sf[kf] = a;
    }

    // online softmax (wave-parallel: shfl_xor over 16-lane key groups)
    float p[4][4];
#pragma unroll
    for (int r = 0; r < 4; ++r) {
      const int qg = qb + w * 16 + lg * 4 + r;
      float mx = -INFINITY;
#pragma unroll
      for (int kf = 0; kf < 4; ++kf) {
        const int kg = kb + kf * 16 + lr;
        const float sv = (kg <= qg) ? sf[kf][r] * scale : -INFINITY;
        p[kf][r] = sv;
        mx = fmaxf(mx, sv);
      }
#pragma unroll
      for (int dd = 1; dd < 16; dd <<= 1) mx = fmaxf(mx, __shfl_xor(mx, dd, 64));
      const float mn = fmaxf(m[r], mx);
      const float sc = __expf(m[r] - mn);
      float sum = 0.f;
#pragma unroll
      for (int kf = 0; kf < 4; ++kf) {
        const float pe = __expf(p[kf][r] - mn);
        p[kf][r] = pe;
        sum += pe;
      }
#pragma unroll
      for (int dd = 1; dd < 16; dd <<= 1) sum += __shfl_xor(sum, dd, 64);
      l[r] = l[r] * sc + sum;
      m[r] = mn;
#pragma unroll
      for (int f = 0; f < 8; ++f) o[f][r] *= sc;
    }

    // P -> LDS (per-wave buffer), then PV
#pragma unroll
    for (int kf = 0; kf < 4; ++kf)
#pragma unroll
      for (int r = 0; r < 4; ++r)
        lP[w][(lg * 4 + r) * 72 + kf * 16 + lr] = f2b(p[kf][r]);
    asm volatile("s_waitcnt lgkmcnt(0)" ::: "memory");

#pragma unroll
    for (int kh = 0; kh < 2; ++kh) {
      const bf16x8 pa = *(const bf16x8*)(&lP[w][lr * 72 + kh * 32 + lg * 8]);
#pragma unroll
      for (int f = 0; f < 8; ++f) {
        const int d = f * 16 + lr;
        const int sw = (kh * 4 + lg) ^ (d & 7);
        const bf16x8 vb = *(const bf16x8*)(lV + d * 64 + sw * 8);
        o[f] = __builtin_amdgcn_mfma_f32_16x16x32_bf16(pa, vb, o[f], 0, 0, 0);
      }
    }
  }

  // epilogue: O /= l, write bf16 to attn_b[s][h*128+d]
#pragma unroll
  for (int r = 0; r < 4; ++r) {
    const float inv = 1.0f / l[r];
    const size_t base = (size_t)(qb + w * 16 + lg * 4 + r) * HDIM + h * 128;
#pragma unroll
    for (int f = 0; f < 8; ++f) attn_b[base + f * 16 + lr] = f2b(o[f][r] * inv);
  }
}

// ---------------- launch ----------------
extern "C" void kernel_launch(void* const* d_in, const int* in_sizes, int n_in,
                              void* d_out, int out_size, void* d_ws, size_t ws_size,
                              hipStream_t stream) {
  const float* hidden = (const float*)d_in[0];
  const int* pos_ids = (const int*)d_in[2];
  const float* Wq = (const float*)d_in[3];
  const float* bq = (const float*)d_in[4];
  const float* Wk = (const float*)d_in[5];
  const float* bk = (const float*)d_in[6];
  const float* Wv = (const float*)d_in[7];
  const float* bv = (const float*)d_in[8];
  const float* Wo = (const float*)d_in[9];

  float* out = (float*)d_out;
  float* cache_k = out + (size_t)S_LEN * HDIM;
  float* cache_v = cache_k + (size_t)S_LEN * N_KV * HD_;

  char* ws = (char*)d_ws;
  ushort* x_b = (ushort*)(ws);                      //  0..8MiB  : x bf16 [2048][2048]
  ushort* wt = (ushort*)(ws + (8u << 20));          //  8..18MiB : W^T bf16 [2560][2048]
  ushort* qkv = (ushort*)(ws + (18u << 20));        // 18..28MiB : qkv bf16 [2048][2560]
  ushort* q_r = (ushort*)(ws);                      //  0..8MiB  (reuse x_b)
  ushort* k_r = (ushort*)(ws + (8u << 20));         //  8..9MiB
  ushort* v_t = (ushort*)(ws + (9u << 20));         //  9..10MiB
  ushort* wo_t = (ushort*)(ws + (10u << 20));       // 10..18MiB (reuse wt tail)
  ushort* attn_b = (ushort*)(ws + (18u << 20));     // 18..26MiB (reuse qkv)

  k_f32_to_bf16<<<dim3((S_LEN * HDIM) / 1024), 256, 0, stream>>>(hidden, x_b,
                                                                 (S_LEN * HDIM) / 4);
  k_transpose_bf16<<<dim3(32, 32), 256, 0, stream>>>(Wq, wt, 2048, 2048);
  k_transpose_bf16<<<dim3(4, 32), 256, 0, stream>>>(Wk, wt + (size_t)2048 * 2048, 2048, 256);
  k_transpose_bf16<<<dim3(4, 32), 256, 0, stream>>>(Wv, wt + (size_t)2304 * 2048, 2048, 256);
  k_gemm_bt<0><<<dim3(16, 20), 256, 0, stream>>>(x_b, wt, qkv, bq, bk, bv, 2048, 2560, 2048);
  k_transpose_bf16<<<dim3(32, 32), 256, 0, stream>>>(Wo, wo_t, 2048, 2048);  // after gemm1 (wt dead)
  k_rope<<<dim3(S_LEN), 256, 0, stream>>>(qkv, pos_ids, q_r, k_r, v_t, cache_k, cache_v);
  k_attn<<<dim3(S_LEN / 64, N_H), 256, 0, stream>>>(q_r, k_r, v_t, attn_b);
  k_gemm_bt<1><<<dim3(16, 16), 256, 0, stream>>>(attn_b, wo_t, out, nullptr, nullptr,
                                                 nullptr, 2048, 2048, 2048);
}

// Round 2
// 206.934 us; speedup vs baseline: 1.0737x; 1.0737x over previous
//
#include <hip/hip_runtime.h>
#include <hip/hip_bf16.h>
#include <math.h>

#define S_LEN 2048
#define HDIM  2048
#define N_H   16
#define N_KV  2
#define HD_   128
#define NQKV  2560

typedef __attribute__((ext_vector_type(8))) short bf16x8;
typedef __attribute__((ext_vector_type(4))) float f32x4;
typedef __attribute__((ext_vector_type(16))) float f32x16;

#define GLDS16(gsrc, ldst)                                                      \
  __builtin_amdgcn_global_load_lds(                                             \
      (const __attribute__((address_space(1))) void*)(gsrc),                    \
      (__attribute__((address_space(3))) void*)(ldst), 16, 0, 0)

__device__ __forceinline__ ushort f2b(float x) {
  union { __hip_bfloat16 b; ushort u; } c;
  c.b = __float2bfloat16(x);
  return c.u;
}
__device__ __forceinline__ float b2f(ushort u) {
  union { float f; unsigned v; } c;
  c.v = ((unsigned)u) << 16;
  return c.f;
}
__device__ __forceinline__ uint pk2(float a, float b) {
  return (uint)f2b(a) | ((uint)f2b(b) << 16);
}

// ---------------- f32 -> bf16 elementwise (x conversion) ----------------
__global__ __launch_bounds__(256) void k_f32_to_bf16(const float* __restrict__ src,
                                                     ushort* __restrict__ dst, int n4) {
  int i = blockIdx.x * 256 + threadIdx.x;
  if (i >= n4) return;
  float4 v = ((const float4*)src)[i];
  ushort4 o;
  o.x = f2b(v.x); o.y = f2b(v.y); o.z = f2b(v.z); o.w = f2b(v.w);
  ((ushort4*)dst)[i] = o;
}

// ---------------- f32 [R][C] -> bf16 [C][R] tiled transpose ----------------
__global__ __launch_bounds__(256) void k_transpose_bf16(const float* __restrict__ src,
                                                        ushort* __restrict__ dst,
                                                        int R, int C) {
  __shared__ float t[64][65];
  int c0 = blockIdx.x * 64, r0 = blockIdx.y * 64;
  int tx = threadIdx.x & 63, ty = threadIdx.x >> 6;
#pragma unroll
  for (int i = 0; i < 16; ++i)
    t[i * 4 + ty][tx] = src[(size_t)(r0 + i * 4 + ty) * C + (c0 + tx)];
  __syncthreads();
#pragma unroll
  for (int i = 0; i < 16; ++i)
    dst[(size_t)(c0 + i * 4 + ty) * R + (r0 + tx)] = f2b(t[tx][i * 4 + ty]);
}

// ---------------- bf16 GEMM: C[M][N] = A[M][K] * Bt[N][K]^T ----------------
template <int OUT_MODE>
__global__ __launch_bounds__(256) void k_gemm_bt(const ushort* __restrict__ A,
                                                 const ushort* __restrict__ Bt,
                                                 void* __restrict__ Cp,
                                                 const float* __restrict__ bq,
                                                 const float* __restrict__ bk,
                                                 const float* __restrict__ bv,
                                                 int M, int N, int K) {
  __shared__ ushort lA[128 * 32];
  __shared__ ushort lB[128 * 32];
  const int tid = threadIdx.x;
  const int w = tid >> 6, lane = tid & 63;
  const int lr = lane & 15, lg = lane >> 4;
  const int bm = blockIdx.x * 128, bn = blockIdx.y * 128;
  const int wm = (w >> 1) * 64, wn = (w & 1) * 64;
  f32x4 acc[4][4] = {};

  for (int k0 = 0; k0 < K; k0 += 32) {
    __syncthreads();
#pragma unroll
    for (int it = 0; it < 2; ++it) {
      const int idx = it * 256 + tid;
      const int row = idx >> 2;
      const int kc = (idx & 3) * 8;
      GLDS16(A + (size_t)(bm + row) * K + k0 + kc, lA + (it * 4 + w) * 512);
      GLDS16(Bt + (size_t)(bn + row) * K + k0 + kc, lB + (it * 4 + w) * 512);
    }
    __syncthreads();
    bf16x8 af[4], bf[4];
#pragma unroll
    for (int i = 0; i < 4; ++i) {
      af[i] = *(const bf16x8*)(lA + (wm + i * 16 + lr) * 32 + lg * 8);
      bf[i] = *(const bf16x8*)(lB + (wn + i * 16 + lr) * 32 + lg * 8);
    }
#pragma unroll
    for (int mi = 0; mi < 4; ++mi)
#pragma unroll
      for (int ni = 0; ni < 4; ++ni)
        acc[mi][ni] =
            __builtin_amdgcn_mfma_f32_16x16x32_bf16(af[mi], bf[ni], acc[mi][ni], 0, 0, 0);
  }

#pragma unroll
  for (int mi = 0; mi < 4; ++mi)
#pragma unroll
    for (int ni = 0; ni < 4; ++ni)
#pragma unroll
      for (int r = 0; r < 4; ++r) {
        const int row = bm + wm + mi * 16 + lg * 4 + r;
        const int col = bn + wn + ni * 16 + lr;
        const float v = acc[mi][ni][r];
        if (OUT_MODE == 0) {
          float bias = (col < 2048) ? bq[col] : (col < 2304 ? bk[col - 2048] : bv[col - 2304]);
          float vb = b2f(f2b(v)) + b2f(f2b(bias));  // bf16 add semantics
          ((ushort*)Cp)[(size_t)row * N + col] = f2b(vb);
        } else {
          ((float*)Cp)[(size_t)row * N + col] = b2f(f2b(v));  // ref rounds to bf16
        }
      }
}

// ---------------- RoPE + cache writes + V transpose ----------------
// q_r stores q*scale (scale folded in; attention skips the multiply)
__global__ __launch_bounds__(256) void k_rope(const ushort* __restrict__ qkv,
                                              const int* __restrict__ pos_ids,
                                              ushort* __restrict__ q_r,
                                              ushort* __restrict__ k_r,
                                              ushort* __restrict__ v_t,
                                              float* __restrict__ cache_k,
                                              float* __restrict__ cache_v) {
  const int s = blockIdx.x;
  const int t = threadIdx.x;
  const int i = t & 63, g = t >> 6;
  const float SCALE = 0.08838834764831845f;  // 1/sqrt(128)
  const float pos = (float)pos_ids[s];
  const float freq = (float)(1.0 / pow(1000000.0, (double)i / 64.0));
  float sn, cs;
  sincosf(pos * freq, &sn, &cs);
  const ushort* row = qkv + (size_t)s * NQKV;

#pragma unroll
  for (int j = 0; j < 4; ++j) {
    const int h = j * 4 + g;
    const float x1 = b2f(row[h * 128 + i]);
    const float x2 = b2f(row[h * 128 + 64 + i]);
    const float o1 = x1 * cs - x2 * sn;
    const float o2 = x1 * sn + x2 * cs;
    const size_t qo = ((size_t)h * S_LEN + s) * 128;
    q_r[qo + i] = f2b(o1 * SCALE);
    q_r[qo + 64 + i] = f2b(o2 * SCALE);
  }
  if (g < 2) {
    const int kv = g;
    const float x1 = b2f(row[2048 + kv * 128 + i]);
    const float x2 = b2f(row[2048 + kv * 128 + 64 + i]);
    const float o1 = x1 * cs - x2 * sn;
    const float o2 = x1 * sn + x2 * cs;
    const size_t ko = ((size_t)kv * S_LEN + s) * 128;
    k_r[ko + i] = f2b(o1);
    k_r[ko + 64 + i] = f2b(o2);
    const size_t co = ((size_t)s * 2 + kv) * 128;
    cache_k[co + i] = o1;
    cache_k[co + 64 + i] = o2;
  }
  {
    const int kv = t >> 7, d = t & 127;
    const ushort bits = row[2304 + kv * 128 + d];
    cache_v[((size_t)s * 2 + kv) * 128 + d] = b2f(bits);
    v_t[((size_t)kv * 128 + d) * S_LEN + s] = bits;
  }
}

// ---------------- flash attention, swapped-QK 32x32 in-register softmax ----
// 4 warps x 32 q-rows = 128 q/block; grid (16 q-tiles, 16 heads).
// LDS: K[64][128] + V^T[128][64] bf16, double-buffered, 16B-slot XOR swizzle.
__global__ __launch_bounds__(256, 1) void k_attn(const ushort* __restrict__ q_r,
                                                 const ushort* __restrict__ k_r,
                                                 const ushort* __restrict__ v_t,
                                                 ushort* __restrict__ attn_b) {
  __shared__ ushort smem[2][2][64 * 128];  // [K/V][buf] = 64 KiB total
  const int h = blockIdx.y, kvh = h >> 3;
  const int bx = blockIdx.x;
  const int tid = threadIdx.x, w = tid >> 6, lane = tid & 63;
  const int l31 = lane & 31, hb = lane >> 5;
  const int NT = 2 * bx + 2;
  const int qmaxw = bx * 128 + w * 32 + 31;

  // Q fragments (B-operand): lane holds Q[q=l31][hd = f*16 + 8*hb + j]
  bf16x8 qf[8];
  {
    const ushort* qp = q_r + ((size_t)(h * S_LEN + bx * 128 + w * 32 + l31)) * 128 + hb * 8;
#pragma unroll
    for (int f = 0; f < 8; ++f) qf[f] = *(const bf16x8*)(qp + f * 16);
  }

  f32x16 acc[4] = {};  // O^T: [d-group] row=d, col=q
  float m = -INFINITY, l = 0.f;

  // staging helper indices (per thread, per it)
#define STAGE_TILE(BUF, KB)                                                       \
  do {                                                                            \
    _Pragma("unroll") for (int it = 0; it < 4; ++it) {                            \
      const int idx = it * 256 + tid;                                             \
      {                                                                           \
        const int key = idx >> 4, sl = idx & 15;                                  \
        GLDS16(k_r + ((size_t)(kvh * S_LEN + (KB) + key)) * 128 +                 \
                   ((sl ^ (key & 7)) * 8),                                        \
               &smem[0][BUF][(it * 4 + w) * 512]);                                \
      }                                                                           \
      {                                                                           \
        const int d = idx >> 3, sl = idx & 7;                                     \
        GLDS16(v_t + ((size_t)(kvh * HD_ + d)) * S_LEN + (KB) + ((sl ^ (d & 7)) * 8), \
               &smem[1][BUF][(it * 4 + w) * 512]);                                \
      }                                                                           \
    }                                                                             \
  } while (0)

  STAGE_TILE(0, 0);
  int buf = 0;

  for (int t = 0; t < NT; ++t) {
    __syncthreads();  // drains vmcnt: tile t ready, prev buf free
    if (t + 1 < NT) STAGE_TILE(buf ^ 1, (t + 1) * 64);
    const int kb = t * 64;

    if (kb <= qmaxw) {
      const ushort* lKb = &smem[0][buf][0];
      const ushort* lVb = &smem[1][buf][0];

      // QK^T: p[g] = K-group-g x Q -> D[key][q], col=lane&31=q
      f32x16 p0 = {}, p1 = {};
#pragma unroll
      for (int f = 0; f < 8; ++f) {
        const int key0 = l31;
        const bf16x8 k0 = *(const bf16x8*)(lKb + key0 * 128 + (((2 * f + hb) ^ (key0 & 7)) * 8));
        p0 = __builtin_amdgcn_mfma_f32_32x32x16_bf16(k0, qf[f], p0, 0, 0, 0);
      }
#pragma unroll
      for (int f = 0; f < 8; ++f) {
        const int key1 = 32 + l31;
        const bf16x8 k1 = *(const bf16x8*)(lKb + key1 * 128 + (((2 * f + hb) ^ (key1 & 7)) * 8));
        p1 = __builtin_amdgcn_mfma_f32_32x32x16_bf16(k1, qf[f], p1, 0, 0, 0);
      }

      // causal mask + online softmax (per-lane row, one cross-half shuffle)
      const int q = bx * 128 + w * 32 + l31;
      float sv[32];
      float mx = -INFINITY;
#pragma unroll
      for (int r = 0; r < 16; ++r) {
        const int key = kb + (r & 3) + 8 * (r >> 2) + 4 * hb;
        sv[r] = (key <= q) ? p0[r] : -INFINITY;
        mx = fmaxf(mx, sv[r]);
      }
#pragma unroll
      for (int r = 0; r < 16; ++r) {
        const int key = kb + 32 + (r & 3) + 8 * (r >> 2) + 4 * hb;
        sv[16 + r] = (key <= q) ? p1[r] : -INFINITY;
        mx = fmaxf(mx, sv[16 + r]);
      }
      mx = fmaxf(mx, __shfl_xor(mx, 32));
      const float mn = fmaxf(m, mx);
      const float sc = __expf(m - mn);
      float lsum = 0.f;
#pragma unroll
      for (int r = 0; r < 32; ++r) {
        sv[r] = __expf(sv[r] - mn);
        lsum += sv[r];
      }
      l = l * sc + lsum;
      m = mn;
#pragma unroll
      for (int g2 = 0; g2 < 4; ++g2)
#pragma unroll
        for (int r = 0; r < 16; ++r) acc[g2][r] *= sc;

      // P -> bf16 fragments (in-register, cross-half exchange via shfl_xor 32)
      uint pk8[2][8];
#pragma unroll
      for (int j = 0; j < 8; ++j) {
        pk8[0][j] = pk2(sv[2 * j], sv[2 * j + 1]);
        pk8[1][j] = pk2(sv[16 + 2 * j], sv[16 + 2 * j + 1]);
      }
      union FragU { uint wd[4]; bf16x8 v; };
      FragU frag[4];
#pragma unroll
      for (int g = 0; g < 2; ++g)
#pragma unroll
        for (int c1 = 0; c1 < 2; ++c1) {
          uint mine0, mine1, rcv0, rcv1;
          {
            const uint pa = pk8[g][0 + 4 * c1];      // h'=0, w1=0
            const uint pb = pk8[g][2 + 4 * c1];      // h'=1, w1=0
            const uint mn_ = hb ? pb : pa;
            const uint xc_ = hb ? pa : pb;
            mine0 = mn_;
            rcv0 = (uint)__shfl_xor((int)xc_, 32);
          }
          {
            const uint pa = pk8[g][1 + 4 * c1];      // h'=0, w1=1
            const uint pb = pk8[g][3 + 4 * c1];      // h'=1, w1=1
            const uint mn_ = hb ? pb : pa;
            const uint xc_ = hb ? pa : pb;
            mine1 = mn_;
            rcv1 = (uint)__shfl_xor((int)xc_, 32);
          }
          const int c = 2 * g + c1;
          frag[c].wd[0] = hb ? rcv0 : mine0;
          frag[c].wd[1] = hb ? rcv1 : mine1;
          frag[c].wd[2] = hb ? mine0 : rcv0;
          frag[c].wd[3] = hb ? mine1 : rcv1;
        }

      // PV: acc[g2] += V^T[d-group g2] x P  (A from LDS, B in-register)
#pragma unroll
      for (int g2 = 0; g2 < 4; ++g2) {
        const int d = g2 * 32 + l31;
#pragma unroll
        for (int c = 0; c < 4; ++c) {
          const bf16x8 vf = *(const bf16x8*)(lVb + d * 64 + (((2 * c + hb) ^ (d & 7)) * 8));
          acc[g2] = __builtin_amdgcn_mfma_f32_32x32x16_bf16(vf, frag[c].v, acc[g2], 0, 0, 0);
        }
      }
    }
    buf ^= 1;
  }

  // epilogue: normalize, transpose via LDS (XOR-swizzled), coalesced store
  {
    const float lt = l + __shfl_xor(l, 32);
    const float inv = 1.0f / lt;
    __syncthreads();  // staging LDS reuse
    float* ldsO = ((float*)smem) + w * 4096;  // 32 q x 128 d per warp
#pragma unroll
    for (int g2 = 0; g2 < 4; ++g2)
#pragma unroll
      for (int r = 0; r < 16; ++r) {
        const int d5 = (r & 3) + 8 * (r >> 2) + 4 * hb;
        ldsO[l31 * 128 + g2 * 32 + (d5 ^ l31)] = acc[g2][r] * inv;
      }
#pragma unroll
    for (int pass = 0; pass < 8; ++pass) {
      const int qrow = pass * 4 + (lane >> 4);
      const int d0 = (lane & 15) * 8;
      float v[8];
#pragma unroll
      for (int j = 0; j < 8; ++j)
        v[j] = ldsO[qrow * 128 + (((d0 + j) & 31) ^ qrow) + (d0 & 96)];
      uint4 o;
      o.x = pk2(v[0], v[1]); o.y = pk2(v[2], v[3]);
      o.z = pk2(v[4], v[5]); o.w = pk2(v[6], v[7]);
      const size_t qg = (size_t)(bx * 128 + w * 32 + qrow);
      *(uint4*)(attn_b + qg * HDIM + h * 128 + d0) = o;
    }
  }
#undef STAGE_TILE
}

// ---------------- launch ----------------
extern "C" void kernel_launch(void* const* d_in, const int* in_sizes, int n_in,
                              void* d_out, int out_size, void* d_ws, size_t ws_size,
                              hipStream_t stream) {
  const float* hidden = (const float*)d_in[0];
  const int* pos_ids = (const int*)d_in[2];
  const float* Wq = (const float*)d_in[3];
  const float* bq = (const float*)d_in[4];
  const float* Wk = (const float*)d_in[5];
  const float* bk = (const float*)d_in[6];
  const float* Wv = (const float*)d_in[7];
  const float* bv = (const float*)d_in[8];
  const float* Wo = (const float*)d_in[9];

  float* out = (float*)d_out;
  float* cache_k = out + (size_t)S_LEN * HDIM;
  float* cache_v = cache_k + (size_t)S_LEN * N_KV * HD_;

  char* ws = (char*)d_ws;
  ushort* x_b = (ushort*)(ws);                      //  0..8MiB  : x bf16 [2048][2048]
  ushort* wt = (ushort*)(ws + (8u << 20));          //  8..18MiB : W^T bf16 [2560][2048]
  ushort* qkv = (ushort*)(ws + (18u << 20));        // 18..28MiB : qkv bf16 [2048][2560]
  ushort* q_r = (ushort*)(ws);                      //  0..8MiB  (reuse x_b)
  ushort* k_r = (ushort*)(ws + (8u << 20));         //  8..9MiB
  ushort* v_t = (ushort*)(ws + (9u << 20));         //  9..10MiB
  ushort* wo_t = (ushort*)(ws + (10u << 20));       // 10..18MiB (reuse wt tail)
  ushort* attn_b = (ushort*)(ws + (18u << 20));     // 18..26MiB (reuse qkv)

  k_f32_to_bf16<<<dim3((S_LEN * HDIM) / 1024), 256, 0, stream>>>(hidden, x_b,
                                                                 (S_LEN * HDIM) / 4);
  k_transpose_bf16<<<dim3(32, 32), 256, 0, stream>>>(Wq, wt, 2048, 2048);
  k_transpose_bf16<<<dim3(4, 32), 256, 0, stream>>>(Wk, wt + (size_t)2048 * 2048, 2048, 256);
  k_transpose_bf16<<<dim3(4, 32), 256, 0, stream>>>(Wv, wt + (size_t)2304 * 2048, 2048, 256);
  k_gemm_bt<0><<<dim3(16, 20), 256, 0, stream>>>(x_b, wt, qkv, bq, bk, bv, 2048, 2560, 2048);
  k_transpose_bf16<<<dim3(32, 32), 256, 0, stream>>>(Wo, wo_t, 2048, 2048);
  k_rope<<<dim3(S_LEN), 256, 0, stream>>>(qkv, pos_ids, q_r, k_r, v_t, cache_k, cache_v);
  k_attn<<<dim3(S_LEN / 128, N_H), 256, 0, stream>>>(q_r, k_r, v_t, attn_b);
  k_gemm_bt<1><<<dim3(16, 16), 256, 0, stream>>>(attn_b, wo_t, out, nullptr, nullptr,
                                                 nullptr, 2048, 2048, 2048);
}

// Round 3
// 168.948 us; speedup vs baseline: 1.3151x; 1.2248x over previous
//
#include <hip/hip_runtime.h>
#include <hip/hip_bf16.h>
#include <math.h>

#define S_LEN 2048
#define HDIM  2048
#define N_H   16
#define N_KV  2
#define HD_   128
#define NQKV  2560

typedef __attribute__((ext_vector_type(8))) short bf16x8;
typedef __attribute__((ext_vector_type(4))) float f32x4;
typedef __attribute__((ext_vector_type(16))) float f32x16;

#define GLDS16(gsrc, ldst)                                                      \
  __builtin_amdgcn_global_load_lds(                                             \
      (const __attribute__((address_space(1))) void*)(gsrc),                    \
      (__attribute__((address_space(3))) void*)(ldst), 16, 0, 0)

__device__ __forceinline__ ushort f2b(float x) {
  union { __hip_bfloat16 b; ushort u; } c;
  c.b = __float2bfloat16(x);
  return c.u;
}
__device__ __forceinline__ float b2f(ushort u) {
  union { float f; unsigned v; } c;
  c.v = ((unsigned)u) << 16;
  return c.f;
}
__device__ __forceinline__ uint pk2(float a, float b) {
  return (uint)f2b(a) | ((uint)f2b(b) << 16);
}

// ---------------- f32 -> bf16 elementwise (x conversion) ----------------
__global__ __launch_bounds__(256) void k_f32_to_bf16(const float* __restrict__ src,
                                                     ushort* __restrict__ dst, int n4) {
  int i = blockIdx.x * 256 + threadIdx.x;
  if (i >= n4) return;
  float4 v = ((const float4*)src)[i];
  ushort4 o;
  o.x = f2b(v.x); o.y = f2b(v.y); o.z = f2b(v.z); o.w = f2b(v.w);
  ((ushort4*)dst)[i] = o;
}

// ---------------- f32 [R][C] -> bf16 [C][R] tiled transpose ----------------
__global__ __launch_bounds__(256) void k_transpose_bf16(const float* __restrict__ src,
                                                        ushort* __restrict__ dst,
                                                        int R, int C) {
  __shared__ float t[64][65];
  int c0 = blockIdx.x * 64, r0 = blockIdx.y * 64;
  int tx = threadIdx.x & 63, ty = threadIdx.x >> 6;
#pragma unroll
  for (int i = 0; i < 16; ++i)
    t[i * 4 + ty][tx] = src[(size_t)(r0 + i * 4 + ty) * C + (c0 + tx)];
  __syncthreads();
#pragma unroll
  for (int i = 0; i < 16; ++i)
    dst[(size_t)(c0 + i * 4 + ty) * R + (r0 + tx)] = f2b(t[tx][i * 4 + ty]);
}

// ---------------- bf16 GEMM 128x64 tile: C[M][N] = A[M][K] * Bt[N][K]^T ----
// 640/512 blocks -> ~2.5 blocks/CU for TLP (was 1.25 at 128x128).
template <int OUT_MODE>
__global__ __launch_bounds__(256) void k_gemm_bt(const ushort* __restrict__ A,
                                                 const ushort* __restrict__ Bt,
                                                 void* __restrict__ Cp,
                                                 const float* __restrict__ bq,
                                                 const float* __restrict__ bk,
                                                 const float* __restrict__ bv,
                                                 int M, int N, int K) {
  __shared__ ushort lA[128 * 32];
  __shared__ ushort lB[64 * 32];
  const int tid = threadIdx.x;
  const int w = tid >> 6, lane = tid & 63;
  const int lr = lane & 15, lg = lane >> 4;
  const int bm = blockIdx.x * 128, bn = blockIdx.y * 64;
  const int wm = (w >> 1) * 64, wn = (w & 1) * 32;
  f32x4 acc[4][2] = {};

  for (int k0 = 0; k0 < K; k0 += 32) {
    __syncthreads();
#pragma unroll
    for (int it = 0; it < 2; ++it) {
      const int idx = it * 256 + tid;
      const int row = idx >> 2;
      const int kc = (idx & 3) * 8;
      GLDS16(A + (size_t)(bm + row) * K + k0 + kc, lA + (it * 4 + w) * 512);
    }
    {
      const int row = tid >> 2;
      const int kc = (tid & 3) * 8;
      GLDS16(Bt + (size_t)(bn + row) * K + k0 + kc, lB + w * 512);
    }
    __syncthreads();
    bf16x8 af[4], bf[2];
#pragma unroll
    for (int i = 0; i < 4; ++i)
      af[i] = *(const bf16x8*)(lA + (wm + i * 16 + lr) * 32 + lg * 8);
#pragma unroll
    for (int i = 0; i < 2; ++i)
      bf[i] = *(const bf16x8*)(lB + (wn + i * 16 + lr) * 32 + lg * 8);
    __builtin_amdgcn_s_setprio(1);
#pragma unroll
    for (int mi = 0; mi < 4; ++mi)
#pragma unroll
      for (int ni = 0; ni < 2; ++ni)
        acc[mi][ni] =
            __builtin_amdgcn_mfma_f32_16x16x32_bf16(af[mi], bf[ni], acc[mi][ni], 0, 0, 0);
    __builtin_amdgcn_s_setprio(0);
  }

#pragma unroll
  for (int mi = 0; mi < 4; ++mi)
#pragma unroll
    for (int ni = 0; ni < 2; ++ni)
#pragma unroll
      for (int r = 0; r < 4; ++r) {
        const int row = bm + wm + mi * 16 + lg * 4 + r;
        const int col = bn + wn + ni * 16 + lr;
        const float v = acc[mi][ni][r];
        if (OUT_MODE == 0) {
          float bias = (col < 2048) ? bq[col] : (col < 2304 ? bk[col - 2048] : bv[col - 2304]);
          float vb = b2f(f2b(v)) + b2f(f2b(bias));  // bf16 add semantics
          ((ushort*)Cp)[(size_t)row * N + col] = f2b(vb);
        } else {
          ((float*)Cp)[(size_t)row * N + col] = b2f(f2b(v));  // ref rounds to bf16
        }
      }
}

// ---------------- RoPE + cache writes + V transpose ----------------
__global__ __launch_bounds__(256) void k_rope(const ushort* __restrict__ qkv,
                                              const int* __restrict__ pos_ids,
                                              ushort* __restrict__ q_r,
                                              ushort* __restrict__ k_r,
                                              ushort* __restrict__ v_t,
                                              float* __restrict__ cache_k,
                                              float* __restrict__ cache_v) {
  const int s = blockIdx.x;
  const int t = threadIdx.x;
  const int i = t & 63, g = t >> 6;
  const float SCALE = 0.08838834764831845f;  // 1/sqrt(128)
  const float pos = (float)pos_ids[s];
  const float freq = (float)(1.0 / pow(1000000.0, (double)i / 64.0));
  float sn, cs;
  sincosf(pos * freq, &sn, &cs);
  const ushort* row = qkv + (size_t)s * NQKV;

#pragma unroll
  for (int j = 0; j < 4; ++j) {
    const int h = j * 4 + g;
    const float x1 = b2f(row[h * 128 + i]);
    const float x2 = b2f(row[h * 128 + 64 + i]);
    const float o1 = x1 * cs - x2 * sn;
    const float o2 = x1 * sn + x2 * cs;
    const size_t qo = ((size_t)h * S_LEN + s) * 128;
    q_r[qo + i] = f2b(o1 * SCALE);
    q_r[qo + 64 + i] = f2b(o2 * SCALE);
  }
  if (g < 2) {
    const int kv = g;
    const float x1 = b2f(row[2048 + kv * 128 + i]);
    const float x2 = b2f(row[2048 + kv * 128 + 64 + i]);
    const float o1 = x1 * cs - x2 * sn;
    const float o2 = x1 * sn + x2 * cs;
    const size_t ko = ((size_t)kv * S_LEN + s) * 128;
    k_r[ko + i] = f2b(o1);
    k_r[ko + 64 + i] = f2b(o2);
    const size_t co = ((size_t)s * 2 + kv) * 128;
    cache_k[co + i] = o1;
    cache_k[co + 64 + i] = o2;
  }
  {
    const int kv = t >> 7, d = t & 127;
    const ushort bits = row[2304 + kv * 128 + d];
    cache_v[((size_t)s * 2 + kv) * 128 + d] = b2f(bits);
    v_t[((size_t)kv * 128 + d) * S_LEN + s] = bits;
  }
}

// ---------------- flash attention: qt64, in-block KV-split-2 ---------------
// 512 blocks x 4 waves; warps {0,1}=group0 (even KV tiles), {2,3}=group1 (odd).
// LDS 64KB -> 2 blocks/CU = 2 waves/SIMD. End-merge of the two online states.
__global__ __launch_bounds__(256, 2) void k_attn(const ushort* __restrict__ q_r,
                                                 const ushort* __restrict__ k_r,
                                                 const ushort* __restrict__ v_t,
                                                 ushort* __restrict__ attn_b) {
  __shared__ ushort smem[2][2][8192];  // [group][K/V][64*128] = 64KB
  __shared__ float stats[2][32][2];    // [wq][q_l31][{m,l_total}] from group1

  // blockIdx decode: complementary work for CU-mates under i±1 / i±8 pairing
  const int bi = blockIdx.x;
  const int dir = (bi ^ (bi >> 3)) & 1;
  const int t4 = ((bi >> 1) & 3) | (((bi >> 4) & 3) << 2);
  const int h = ((bi >> 3) & 1) | (((bi >> 6) & 7) << 1);
  const int Q = dir ? (31 - t4) : t4;  // qt64 index 0..31
  const int kvh = h >> 3;

  const int tid = threadIdx.x, w = tid >> 6, lane = tid & 63;
  const int g = w >> 1, wq = w & 1, tg = tid & 127;
  const int l31 = lane & 31, hb = lane >> 5;
  const int NT = Q + 1;                    // 64-key tiles
  const int qmaxw = Q * 64 + wq * 32 + 31; // warp's max q row
  const int S_steps = (Q + 2) >> 1;

  // Q fragments (B-operand): lane holds Q[q=l31][hd = f*16 + 8*hb + j]
  bf16x8 qf[8];
  {
    const ushort* qp =
        q_r + ((size_t)(h * S_LEN + Q * 64 + wq * 32 + l31)) * 128 + hb * 8;
#pragma unroll
    for (int f = 0; f < 8; ++f) qf[f] = *(const bf16x8*)(qp + f * 16);
  }

  f32x16 acc[4] = {};  // O^T: [d-group] row=d, col=q
  float m = -INFINITY, l = 0.f;

  for (int s = 0; s < S_steps; ++s) {
    const int t = 2 * s + g;
    const bool have = (t < NT);
    if (have) {
      const int kb = t * 64;
#pragma unroll
      for (int it = 0; it < 8; ++it) {
        const int idx = it * 128 + tg;
        {  // K tile [64 key][128 d], 16B-slot XOR swizzle by key&7
          const int key = idx >> 4, sl = idx & 15;
          GLDS16(k_r + ((size_t)(kvh * S_LEN + kb + key)) * 128 + ((sl ^ (key & 7)) * 8),
                 &smem[g][0][it * 1024 + wq * 512]);
        }
        {  // V^T tile [128 d][64 key], swizzle by d&7
          const int d = idx >> 3, sl = idx & 7;
          GLDS16(v_t + ((size_t)(kvh * HD_ + d)) * S_LEN + kb + ((sl ^ (d & 7)) * 8),
                 &smem[g][1][it * 1024 + wq * 512]);
        }
      }
    }
    __syncthreads();  // staging drained (vmcnt(0) at barrier)

    const int kb = t * 64;
    if (have && kb <= qmaxw) {
      const ushort* lKb = &smem[g][0][0];
      const ushort* lVb = &smem[g][1][0];

      f32x16 p0 = {}, p1 = {};
      __builtin_amdgcn_s_setprio(1);
#pragma unroll
      for (int f = 0; f < 8; ++f) {
        const int key0 = l31;
        const bf16x8 k0 = *(const bf16x8*)(lKb + key0 * 128 + (((2 * f + hb) ^ (key0 & 7)) * 8));
        p0 = __builtin_amdgcn_mfma_f32_32x32x16_bf16(k0, qf[f], p0, 0, 0, 0);
      }
#pragma unroll
      for (int f = 0; f < 8; ++f) {
        const int key1 = 32 + l31;
        const bf16x8 k1 = *(const bf16x8*)(lKb + key1 * 128 + (((2 * f + hb) ^ (key1 & 7)) * 8));
        p1 = __builtin_amdgcn_mfma_f32_32x32x16_bf16(k1, qf[f], p1, 0, 0, 0);
      }
      __builtin_amdgcn_s_setprio(0);

      // causal mask + tree max
      const int q = Q * 64 + wq * 32 + l31;
      float sv[32];
#pragma unroll
      for (int r = 0; r < 16; ++r) {
        const int key = kb + (r & 3) + 8 * (r >> 2) + 4 * hb;
        sv[r] = (key <= q) ? p0[r] : -INFINITY;
      }
#pragma unroll
      for (int r = 0; r < 16; ++r) {
        const int key = kb + 32 + (r & 3) + 8 * (r >> 2) + 4 * hb;
        sv[16 + r] = (key <= q) ? p1[r] : -INFINITY;
      }
      float tmx[16];
#pragma unroll
      for (int j = 0; j < 16; ++j) tmx[j] = fmaxf(sv[j], sv[j + 16]);
#pragma unroll
      for (int st = 8; st >= 1; st >>= 1)
#pragma unroll
        for (int j = 0; j < 8; ++j)
          if (j < st) tmx[j] = fmaxf(tmx[j], tmx[j + st]);
      const float mxw = fmaxf(tmx[0], __shfl_xor(tmx[0], 32));

      // defer-max (T13): rescale only when new max exceeds m+8
      if (__any(mxw > m + 8.f)) {
        const float mn = fmaxf(m, mxw);
        const float sc = __expf(m - mn);
#pragma unroll
        for (int g2 = 0; g2 < 4; ++g2)
#pragma unroll
          for (int r = 0; r < 16; ++r) acc[g2][r] *= sc;
        l *= sc;
        m = mn;
      }
      float ts[16];
#pragma unroll
      for (int r = 0; r < 32; ++r) sv[r] = __expf(sv[r] - m);
#pragma unroll
      for (int j = 0; j < 16; ++j) ts[j] = sv[j] + sv[j + 16];
#pragma unroll
      for (int st = 8; st >= 1; st >>= 1)
#pragma unroll
        for (int j = 0; j < 8; ++j)
          if (j < st) ts[j] += ts[j + st];
      l += ts[0];

      // P -> bf16 fragments (in-register, cross-half exchange via shfl_xor 32)
      uint pk8[2][8];
#pragma unroll
      for (int j = 0; j < 8; ++j) {
        pk8[0][j] = pk2(sv[2 * j], sv[2 * j + 1]);
        pk8[1][j] = pk2(sv[16 + 2 * j], sv[16 + 2 * j + 1]);
      }
      union FragU { uint wd[4]; bf16x8 v; };
      FragU frag[4];
#pragma unroll
      for (int gg = 0; gg < 2; ++gg)
#pragma unroll
        for (int c1 = 0; c1 < 2; ++c1) {
          uint mine0, mine1, rcv0, rcv1;
          {
            const uint pa = pk8[gg][0 + 4 * c1];
            const uint pb = pk8[gg][2 + 4 * c1];
            const uint mn_ = hb ? pb : pa;
            const uint xc_ = hb ? pa : pb;
            mine0 = mn_;
            rcv0 = (uint)__shfl_xor((int)xc_, 32);
          }
          {
            const uint pa = pk8[gg][1 + 4 * c1];
            const uint pb = pk8[gg][3 + 4 * c1];
            const uint mn_ = hb ? pb : pa;
            const uint xc_ = hb ? pa : pb;
            mine1 = mn_;
            rcv1 = (uint)__shfl_xor((int)xc_, 32);
          }
          const int c = 2 * gg + c1;
          frag[c].wd[0] = hb ? rcv0 : mine0;
          frag[c].wd[1] = hb ? rcv1 : mine1;
          frag[c].wd[2] = hb ? mine0 : rcv0;
          frag[c].wd[3] = hb ? mine1 : rcv1;
        }

      // PV: acc[g2] += V^T[d-group g2] x P
      __builtin_amdgcn_s_setprio(1);
#pragma unroll
      for (int g2 = 0; g2 < 4; ++g2) {
        const int d = g2 * 32 + l31;
#pragma unroll
        for (int c = 0; c < 4; ++c) {
          const bf16x8 vf = *(const bf16x8*)(lVb + d * 64 + (((2 * c + hb) ^ (d & 7)) * 8));
          acc[g2] = __builtin_amdgcn_mfma_f32_32x32x16_bf16(vf, frag[c].v, acc[g2], 0, 0, 0);
        }
      }
      __builtin_amdgcn_s_setprio(0);
    }
    __syncthreads();  // group's warps done reading before next-stage overwrite
  }

  // -------- merge group1 state into group0, then store --------
  float* mrg = (float*)&smem[0][0][0];   // [wq][128 d][32 q] = 32KB
  float* ldsO = (float*)&smem[1][0][0];  // [wq][32 q][128 d] = 32KB
  if (g == 1) {
    const float lt1 = l + __shfl_xor(l, 32);
#pragma unroll
    for (int g2 = 0; g2 < 4; ++g2)
#pragma unroll
      for (int r = 0; r < 16; ++r) {
        const int d5 = (r & 3) + 8 * (r >> 2) + 4 * hb;
        mrg[wq * 4096 + (g2 * 32 + d5) * 32 + l31] = acc[g2][r];
      }
    if (hb == 0) {
      stats[wq][l31][0] = m;
      stats[wq][l31][1] = lt1;
    }
  }
  __syncthreads();
  if (g == 0) {
    const float m1 = stats[wq][l31][0];
    const float l1 = stats[wq][l31][1];
    const float l0 = l + __shfl_xor(l, 32);
    const float ms = fmaxf(m, m1);
    const float f0 = __expf(m - ms);
    const float f1 = __expf(m1 - ms);
    const float inv = 1.0f / (l0 * f0 + l1 * f1);
#pragma unroll
    for (int g2 = 0; g2 < 4; ++g2)
#pragma unroll
      for (int r = 0; r < 16; ++r) {
        const int d5 = (r & 3) + 8 * (r >> 2) + 4 * hb;
        const float o1v = mrg[wq * 4096 + (g2 * 32 + d5) * 32 + l31];
        const float val = (acc[g2][r] * f0 + o1v * f1) * inv;
        ldsO[wq * 4096 + l31 * 128 + g2 * 32 + (d5 ^ l31)] = val;
      }
#pragma unroll
    for (int pass = 0; pass < 8; ++pass) {
      const int qrow = pass * 4 + (lane >> 4);
      const int d0 = (lane & 15) * 8;
      float v[8];
#pragma unroll
      for (int j = 0; j < 8; ++j)
        v[j] = ldsO[wq * 4096 + qrow * 128 + (((d0 + j) & 31) ^ qrow) + (d0 & 96)];
      uint4 o;
      o.x = pk2(v[0], v[1]); o.y = pk2(v[2], v[3]);
      o.z = pk2(v[4], v[5]); o.w = pk2(v[6], v[7]);
      const size_t qg = (size_t)(Q * 64 + wq * 32 + qrow);
      *(uint4*)(attn_b + qg * HDIM + h * 128 + d0) = o;
    }
  }
}

// ---------------- launch ----------------
extern "C" void kernel_launch(void* const* d_in, const int* in_sizes, int n_in,
                              void* d_out, int out_size, void* d_ws, size_t ws_size,
                              hipStream_t stream) {
  const float* hidden = (const float*)d_in[0];
  const int* pos_ids = (const int*)d_in[2];
  const float* Wq = (const float*)d_in[3];
  const float* bq = (const float*)d_in[4];
  const float* Wk = (const float*)d_in[5];
  const float* bk = (const float*)d_in[6];
  const float* Wv = (const float*)d_in[7];
  const float* bv = (const float*)d_in[8];
  const float* Wo = (const float*)d_in[9];

  float* out = (float*)d_out;
  float* cache_k = out + (size_t)S_LEN * HDIM;
  float* cache_v = cache_k + (size_t)S_LEN * N_KV * HD_;

  char* ws = (char*)d_ws;
  ushort* x_b = (ushort*)(ws);                      //  0..8MiB  : x bf16
  ushort* wt = (ushort*)(ws + (8u << 20));          //  8..18MiB : W^T bf16
  ushort* qkv = (ushort*)(ws + (18u << 20));        // 18..28MiB : qkv bf16
  ushort* q_r = (ushort*)(ws);                      //  0..8MiB  (reuse x_b)
  ushort* k_r = (ushort*)(ws + (8u << 20));         //  8..9MiB
  ushort* v_t = (ushort*)(ws + (9u << 20));         //  9..10MiB
  ushort* wo_t = (ushort*)(ws + (10u << 20));       // 10..18MiB
  ushort* attn_b = (ushort*)(ws + (18u << 20));     // 18..26MiB (reuse qkv)

  k_f32_to_bf16<<<dim3((S_LEN * HDIM) / 1024), 256, 0, stream>>>(hidden, x_b,
                                                                 (S_LEN * HDIM) / 4);
  k_transpose_bf16<<<dim3(32, 32), 256, 0, stream>>>(Wq, wt, 2048, 2048);
  k_transpose_bf16<<<dim3(4, 32), 256, 0, stream>>>(Wk, wt + (size_t)2048 * 2048, 2048, 256);
  k_transpose_bf16<<<dim3(4, 32), 256, 0, stream>>>(Wv, wt + (size_t)2304 * 2048, 2048, 256);
  k_gemm_bt<0><<<dim3(16, 40), 256, 0, stream>>>(x_b, wt, qkv, bq, bk, bv, 2048, 2560, 2048);
  k_transpose_bf16<<<dim3(32, 32), 256, 0, stream>>>(Wo, wo_t, 2048, 2048);
  k_rope<<<dim3(S_LEN), 256, 0, stream>>>(qkv, pos_ids, q_r, k_r, v_t, cache_k, cache_v);
  k_attn<<<dim3(512), 256, 0, stream>>>(q_r, k_r, v_t, attn_b);
  k_gemm_bt<1><<<dim3(16, 32), 256, 0, stream>>>(attn_b, wo_t, out, nullptr, nullptr,
                                                 nullptr, 2048, 2048, 2048);
}

// Round 4
// 168.939 us; speedup vs baseline: 1.3152x; 1.0001x over previous
//
#include <hip/hip_runtime.h>
#include <hip/hip_bf16.h>
#include <math.h>

#define S_LEN 2048
#define HDIM  2048
#define N_H   16
#define N_KV  2
#define HD_   128
#define NQKV  2560

typedef __attribute__((ext_vector_type(8))) short bf16x8;
typedef __attribute__((ext_vector_type(4))) float f32x4;
typedef __attribute__((ext_vector_type(16))) float f32x16;

#define GLDS16(gsrc, ldst)                                                      \
  __builtin_amdgcn_global_load_lds(                                             \
      (const __attribute__((address_space(1))) void*)(gsrc),                    \
      (__attribute__((address_space(3))) void*)(ldst), 16, 0, 0)

__device__ __forceinline__ ushort f2b(float x) {
  union { __hip_bfloat16 b; ushort u; } c;
  c.b = __float2bfloat16(x);
  return c.u;
}
__device__ __forceinline__ float b2f(ushort u) {
  union { float f; unsigned v; } c;
  c.v = ((unsigned)u) << 16;
  return c.f;
}
__device__ __forceinline__ uint pk2(float a, float b) {
  return (uint)f2b(a) | ((uint)f2b(b) << 16);
}

// ---------------- f32 -> bf16 elementwise (x conversion) ----------------
__global__ __launch_bounds__(256) void k_f32_to_bf16(const float* __restrict__ src,
                                                     ushort* __restrict__ dst, int n4) {
  int i = blockIdx.x * 256 + threadIdx.x;
  if (i >= n4) return;
  float4 v = ((const float4*)src)[i];
  ushort4 o;
  o.x = f2b(v.x); o.y = f2b(v.y); o.z = f2b(v.z); o.w = f2b(v.w);
  ((ushort4*)dst)[i] = o;
}

// ---------------- f32 [R][C] -> bf16 [C][R] tiled transpose ----------------
__global__ __launch_bounds__(256) void k_transpose_bf16(const float* __restrict__ src,
                                                        ushort* __restrict__ dst,
                                                        int R, int C) {
  __shared__ float t[64][65];
  int c0 = blockIdx.x * 64, r0 = blockIdx.y * 64;
  int tx = threadIdx.x & 63, ty = threadIdx.x >> 6;
#pragma unroll
  for (int i = 0; i < 16; ++i)
    t[i * 4 + ty][tx] = src[(size_t)(r0 + i * 4 + ty) * C + (c0 + tx)];
  __syncthreads();
#pragma unroll
  for (int i = 0; i < 16; ++i)
    dst[(size_t)(c0 + i * 4 + ty) * R + (r0 + tx)] = f2b(t[tx][i * 4 + ty]);
}

// ---------------- bf16 GEMM 128x64 tile: C[M][N] = A[M][K] * Bt[N][K]^T ----
// 640/512 blocks -> ~2.5 blocks/CU for TLP (was 1.25 at 128x128).
template <int OUT_MODE>
__global__ __launch_bounds__(256) void k_gemm_bt(const ushort* __restrict__ A,
                                                 const ushort* __restrict__ Bt,
                                                 void* __restrict__ Cp,
                                                 const float* __restrict__ bq,
                                                 const float* __restrict__ bk,
                                                 const float* __restrict__ bv,
                                                 int M, int N, int K) {
  __shared__ ushort lA[128 * 32];
  __shared__ ushort lB[64 * 32];
  const int tid = threadIdx.x;
  const int w = tid >> 6, lane = tid & 63;
  const int lr = lane & 15, lg = lane >> 4;
  const int bm = blockIdx.x * 128, bn = blockIdx.y * 64;
  const int wm = (w >> 1) * 64, wn = (w & 1) * 32;
  f32x4 acc[4][2] = {};

  for (int k0 = 0; k0 < K; k0 += 32) {
    __syncthreads();
#pragma unroll
    for (int it = 0; it < 2; ++it) {
      const int idx = it * 256 + tid;
      const int row = idx >> 2;
      const int kc = (idx & 3) * 8;
      GLDS16(A + (size_t)(bm + row) * K + k0 + kc, lA + (it * 4 + w) * 512);
    }
    {
      const int row = tid >> 2;
      const int kc = (tid & 3) * 8;
      GLDS16(Bt + (size_t)(bn + row) * K + k0 + kc, lB + w * 512);
    }
    __syncthreads();
    bf16x8 af[4], bf[2];
#pragma unroll
    for (int i = 0; i < 4; ++i)
      af[i] = *(const bf16x8*)(lA + (wm + i * 16 + lr) * 32 + lg * 8);
#pragma unroll
    for (int i = 0; i < 2; ++i)
      bf[i] = *(const bf16x8*)(lB + (wn + i * 16 + lr) * 32 + lg * 8);
    __builtin_amdgcn_s_setprio(1);
#pragma unroll
    for (int mi = 0; mi < 4; ++mi)
#pragma unroll
      for (int ni = 0; ni < 2; ++ni)
        acc[mi][ni] =
            __builtin_amdgcn_mfma_f32_16x16x32_bf16(af[mi], bf[ni], acc[mi][ni], 0, 0, 0);
    __builtin_amdgcn_s_setprio(0);
  }

#pragma unroll
  for (int mi = 0; mi < 4; ++mi)
#pragma unroll
    for (int ni = 0; ni < 2; ++ni)
#pragma unroll
      for (int r = 0; r < 4; ++r) {
        const int row = bm + wm + mi * 16 + lg * 4 + r;
        const int col = bn + wn + ni * 16 + lr;
        const float v = acc[mi][ni][r];
        if (OUT_MODE == 0) {
          float bias = (col < 2048) ? bq[col] : (col < 2304 ? bk[col - 2048] : bv[col - 2304]);
          float vb = b2f(f2b(v)) + b2f(f2b(bias));  // bf16 add semantics
          ((ushort*)Cp)[(size_t)row * N + col] = f2b(vb);
        } else {
          ((float*)Cp)[(size_t)row * N + col] = b2f(f2b(v));  // ref rounds to bf16
        }
      }
}

// ---------------- RoPE + cache writes + V transpose ----------------
__global__ __launch_bounds__(256) void k_rope(const ushort* __restrict__ qkv,
                                              const int* __restrict__ pos_ids,
                                              ushort* __restrict__ q_r,
                                              ushort* __restrict__ k_r,
                                              ushort* __restrict__ v_t,
                                              float* __restrict__ cache_k,
                                              float* __restrict__ cache_v) {
  const int s = blockIdx.x;
  const int t = threadIdx.x;
  const int i = t & 63, g = t >> 6;
  const float SCALE = 0.08838834764831845f;  // 1/sqrt(128)
  const float pos = (float)pos_ids[s];
  const float freq = (float)(1.0 / pow(1000000.0, (double)i / 64.0));
  float sn, cs;
  sincosf(pos * freq, &sn, &cs);
  const ushort* row = qkv + (size_t)s * NQKV;

#pragma unroll
  for (int j = 0; j < 4; ++j) {
    const int h = j * 4 + g;
    const float x1 = b2f(row[h * 128 + i]);
    const float x2 = b2f(row[h * 128 + 64 + i]);
    const float o1 = x1 * cs - x2 * sn;
    const float o2 = x1 * sn + x2 * cs;
    const size_t qo = ((size_t)h * S_LEN + s) * 128;
    q_r[qo + i] = f2b(o1 * SCALE);
    q_r[qo + 64 + i] = f2b(o2 * SCALE);
  }
  if (g < 2) {
    const int kv = g;
    const float x1 = b2f(row[2048 + kv * 128 + i]);
    const float x2 = b2f(row[2048 + kv * 128 + 64 + i]);
    const float o1 = x1 * cs - x2 * sn;
    const float o2 = x1 * sn + x2 * cs;
    const size_t ko = ((size_t)kv * S_LEN + s) * 128;
    k_r[ko + i] = f2b(o1);
    k_r[ko + 64 + i] = f2b(o2);
    const size_t co = ((size_t)s * 2 + kv) * 128;
    cache_k[co + i] = o1;
    cache_k[co + 64 + i] = o2;
  }
  {
    const int kv = t >> 7, d = t & 127;
    const ushort bits = row[2304 + kv * 128 + d];
    cache_v[((size_t)s * 2 + kv) * 128 + d] = b2f(bits);
    v_t[((size_t)kv * 128 + d) * S_LEN + s] = bits;
  }
}

// ---------------- flash attention: qt64, in-block KV-split-2 ---------------
// 512 blocks x 4 waves; warps {0,1}=group0 (even KV tiles), {2,3}=group1 (odd).
// LDS 64KB -> 2 blocks/CU = 2 waves/SIMD. End-merge of the two online states.
__global__ __launch_bounds__(256, 2) void k_attn(const ushort* __restrict__ q_r,
                                                 const ushort* __restrict__ k_r,
                                                 const ushort* __restrict__ v_t,
                                                 ushort* __restrict__ attn_b) {
  __shared__ ushort smem[2][2][8192];  // [group][K/V][64*128] = 64KB
  __shared__ float stats[2][32][2];    // [wq][q_l31][{m,l_total}] from group1

  // blockIdx decode: complementary work for CU-mates under i±1 / i±8 pairing
  const int bi = blockIdx.x;
  const int dir = (bi ^ (bi >> 3)) & 1;
  const int t4 = ((bi >> 1) & 3) | (((bi >> 4) & 3) << 2);
  const int h = ((bi >> 3) & 1) | (((bi >> 6) & 7) << 1);
  const int Q = dir ? (31 - t4) : t4;  // qt64 index 0..31
  const int kvh = h >> 3;

  const int tid = threadIdx.x, w = tid >> 6, lane = tid & 63;
  const int g = w >> 1, wq = w & 1, tg = tid & 127;
  const int l31 = lane & 31, hb = lane >> 5;
  const int NT = Q + 1;                    // 64-key tiles
  const int qmaxw = Q * 64 + wq * 32 + 31; // warp's max q row
  const int S_steps = (Q + 2) >> 1;

  // Q fragments (B-operand): lane holds Q[q=l31][hd = f*16 + 8*hb + j]
  bf16x8 qf[8];
  {
    const ushort* qp =
        q_r + ((size_t)(h * S_LEN + Q * 64 + wq * 32 + l31)) * 128 + hb * 8;
#pragma unroll
    for (int f = 0; f < 8; ++f) qf[f] = *(const bf16x8*)(qp + f * 16);
  }

  f32x16 acc[4] = {};  // O^T: [d-group] row=d, col=q
  float m = -INFINITY, l = 0.f;

  for (int s = 0; s < S_steps; ++s) {
    const int t = 2 * s + g;
    const bool have = (t < NT);
    if (have) {
      const int kb = t * 64;
#pragma unroll
      for (int it = 0; it < 8; ++it) {
        const int idx = it * 128 + tg;
        {  // K tile [64 key][128 d], 16B-slot XOR swizzle by key&7
          const int key = idx >> 4, sl = idx & 15;
          GLDS16(k_r + ((size_t)(kvh * S_LEN + kb + key)) * 128 + ((sl ^ (key & 7)) * 8),
                 &smem[g][0][it * 1024 + wq * 512]);
        }
        {  // V^T tile [128 d][64 key], swizzle by d&7
          const int d = idx >> 3, sl = idx & 7;
          GLDS16(v_t + ((size_t)(kvh * HD_ + d)) * S_LEN + kb + ((sl ^ (d & 7)) * 8),
                 &smem[g][1][it * 1024 + wq * 512]);
        }
      }
    }
    __syncthreads();  // staging drained (vmcnt(0) at barrier)

    const int kb = t * 64;
    if (have && kb <= qmaxw) {
      const ushort* lKb = &smem[g][0][0];
      const ushort* lVb = &smem[g][1][0];

      f32x16 p0 = {}, p1 = {};
      __builtin_amdgcn_s_setprio(1);
#pragma unroll
      for (int f = 0; f < 8; ++f) {
        const int key0 = l31;
        const bf16x8 k0 = *(const bf16x8*)(lKb + key0 * 128 + (((2 * f + hb) ^ (key0 & 7)) * 8));
        p0 = __builtin_amdgcn_mfma_f32_32x32x16_bf16(k0, qf[f], p0, 0, 0, 0);
      }
#pragma unroll
      for (int f = 0; f < 8; ++f) {
        const int key1 = 32 + l31;
        const bf16x8 k1 = *(const bf16x8*)(lKb + key1 * 128 + (((2 * f + hb) ^ (key1 & 7)) * 8));
        p1 = __builtin_amdgcn_mfma_f32_32x32x16_bf16(k1, qf[f], p1, 0, 0, 0);
      }
      __builtin_amdgcn_s_setprio(0);

      // causal mask + tree max
      const int q = Q * 64 + wq * 32 + l31;
      float sv[32];
#pragma unroll
      for (int r = 0; r < 16; ++r) {
        const int key = kb + (r & 3) + 8 * (r >> 2) + 4 * hb;
        sv[r] = (key <= q) ? p0[r] : -INFINITY;
      }
#pragma unroll
      for (int r = 0; r < 16; ++r) {
        const int key = kb + 32 + (r & 3) + 8 * (r >> 2) + 4 * hb;
        sv[16 + r] = (key <= q) ? p1[r] : -INFINITY;
      }
      float tmx[16];
#pragma unroll
      for (int j = 0; j < 16; ++j) tmx[j] = fmaxf(sv[j], sv[j + 16]);
#pragma unroll
      for (int st = 8; st >= 1; st >>= 1)
#pragma unroll
        for (int j = 0; j < 8; ++j)
          if (j < st) tmx[j] = fmaxf(tmx[j], tmx[j + st]);
      const float mxw = fmaxf(tmx[0], __shfl_xor(tmx[0], 32));

      // defer-max (T13): rescale only when new max exceeds m+8
      if (__any(mxw > m + 8.f)) {
        const float mn = fmaxf(m, mxw);
        const float sc = __expf(m - mn);
#pragma unroll
        for (int g2 = 0; g2 < 4; ++g2)
#pragma unroll
          for (int r = 0; r < 16; ++r) acc[g2][r] *= sc;
        l *= sc;
        m = mn;
      }
      float ts[16];
#pragma unroll
      for (int r = 0; r < 32; ++r) sv[r] = __expf(sv[r] - m);
#pragma unroll
      for (int j = 0; j < 16; ++j) ts[j] = sv[j] + sv[j + 16];
#pragma unroll
      for (int st = 8; st >= 1; st >>= 1)
#pragma unroll
        for (int j = 0; j < 8; ++j)
          if (j < st) ts[j] += ts[j + st];
      l += ts[0];

      // P -> bf16 fragments (in-register, cross-half exchange via shfl_xor 32)
      uint pk8[2][8];
#pragma unroll
      for (int j = 0; j < 8; ++j) {
        pk8[0][j] = pk2(sv[2 * j], sv[2 * j + 1]);
        pk8[1][j] = pk2(sv[16 + 2 * j], sv[16 + 2 * j + 1]);
      }
      union FragU { uint wd[4]; bf16x8 v; };
      FragU frag[4];
#pragma unroll
      for (int gg = 0; gg < 2; ++gg)
#pragma unroll
        for (int c1 = 0; c1 < 2; ++c1) {
          uint mine0, mine1, rcv0, rcv1;
          {
            const uint pa = pk8[gg][0 + 4 * c1];
            const uint pb = pk8[gg][2 + 4 * c1];
            const uint mn_ = hb ? pb : pa;
            const uint xc_ = hb ? pa : pb;
            mine0 = mn_;
            rcv0 = (uint)__shfl_xor((int)xc_, 32);
          }
          {
            const uint pa = pk8[gg][1 + 4 * c1];
            const uint pb = pk8[gg][3 + 4 * c1];
            const uint mn_ = hb ? pb : pa;
            const uint xc_ = hb ? pa : pb;
            mine1 = mn_;
            rcv1 = (uint)__shfl_xor((int)xc_, 32);
          }
          const int c = 2 * gg + c1;
          frag[c].wd[0] = hb ? rcv0 : mine0;
          frag[c].wd[1] = hb ? rcv1 : mine1;
          frag[c].wd[2] = hb ? mine0 : rcv0;
          frag[c].wd[3] = hb ? mine1 : rcv1;
        }

      // PV: acc[g2] += V^T[d-group g2] x P
      __builtin_amdgcn_s_setprio(1);
#pragma unroll
      for (int g2 = 0; g2 < 4; ++g2) {
        const int d = g2 * 32 + l31;
#pragma unroll
        for (int c = 0; c < 4; ++c) {
          const bf16x8 vf = *(const bf16x8*)(lVb + d * 64 + (((2 * c + hb) ^ (d & 7)) * 8));
          acc[g2] = __builtin_amdgcn_mfma_f32_32x32x16_bf16(vf, frag[c].v, acc[g2], 0, 0, 0);
        }
      }
      __builtin_amdgcn_s_setprio(0);
    }
    __syncthreads();  // group's warps done reading before next-stage overwrite
  }

  // -------- merge group1 state into group0, then store --------
  float* mrg = (float*)&smem[0][0][0];   // [wq][128 d][32 q] = 32KB
  float* ldsO = (float*)&smem[1][0][0];  // [wq][32 q][128 d] = 32KB
  if (g == 1) {
    const float lt1 = l + __shfl_xor(l, 32);
#pragma unroll
    for (int g2 = 0; g2 < 4; ++g2)
#pragma unroll
      for (int r = 0; r < 16; ++r) {
        const int d5 = (r & 3) + 8 * (r >> 2) + 4 * hb;
        mrg[wq * 4096 + (g2 * 32 + d5) * 32 + l31] = acc[g2][r];
      }
    if (hb == 0) {
      stats[wq][l31][0] = m;
      stats[wq][l31][1] = lt1;
    }
  }
  __syncthreads();
  if (g == 0) {
    const float m1 = stats[wq][l31][0];
    const float l1 = stats[wq][l31][1];
    const float l0 = l + __shfl_xor(l, 32);
    const float ms = fmaxf(m, m1);
    const float f0 = __expf(m - ms);
    const float f1 = __expf(m1 - ms);
    const float inv = 1.0f / (l0 * f0 + l1 * f1);
#pragma unroll
    for (int g2 = 0; g2 < 4; ++g2)
#pragma unroll
      for (int r = 0; r < 16; ++r) {
        const int d5 = (r & 3) + 8 * (r >> 2) + 4 * hb;
        const float o1v = mrg[wq * 4096 + (g2 * 32 + d5) * 32 + l31];
        const float val = (acc[g2][r] * f0 + o1v * f1) * inv;
        ldsO[wq * 4096 + l31 * 128 + g2 * 32 + (d5 ^ l31)] = val;
      }
#pragma unroll
    for (int pass = 0; pass < 8; ++pass) {
      const int qrow = pass * 4 + (lane >> 4);
      const int d0 = (lane & 15) * 8;
      float v[8];
#pragma unroll
      for (int j = 0; j < 8; ++j)
        v[j] = ldsO[wq * 4096 + qrow * 128 + (((d0 + j) & 31) ^ qrow) + (d0 & 96)];
      uint4 o;
      o.x = pk2(v[0], v[1]); o.y = pk2(v[2], v[3]);
      o.z = pk2(v[4], v[5]); o.w = pk2(v[6], v[7]);
      const size_t qg = (size_t)(Q * 64 + wq * 32 + qrow);
      *(uint4*)(attn_b + qg * HDIM + h * 128 + d0) = o;
    }
  }
}

// ---------------- launch ----------------
extern "C" void kernel_launch(void* const* d_in, const int* in_sizes, int n_in,
                              void* d_out, int out_size, void* d_ws, size_t ws_size,
                              hipStream_t stream) {
  const float* hidden = (const float*)d_in[0];
  const int* pos_ids = (const int*)d_in[2];
  const float* Wq = (const float*)d_in[3];
  const float* bq = (const float*)d_in[4];
  const float* Wk = (const float*)d_in[5];
  const float* bk = (const float*)d_in[6];
  const float* Wv = (const float*)d_in[7];
  const float* bv = (const float*)d_in[8];
  const float* Wo = (const float*)d_in[9];

  float* out = (float*)d_out;
  float* cache_k = out + (size_t)S_LEN * HDIM;
  float* cache_v = cache_k + (size_t)S_LEN * N_KV * HD_;

  char* ws = (char*)d_ws;
  ushort* x_b = (ushort*)(ws);                      //  0..8MiB  : x bf16
  ushort* wt = (ushort*)(ws + (8u << 20));          //  8..18MiB : W^T bf16
  ushort* qkv = (ushort*)(ws + (18u << 20));        // 18..28MiB : qkv bf16
  ushort* q_r = (ushort*)(ws);                      //  0..8MiB  (reuse x_b)
  ushort* k_r = (ushort*)(ws + (8u << 20));         //  8..9MiB
  ushort* v_t = (ushort*)(ws + (9u << 20));         //  9..10MiB
  ushort* wo_t = (ushort*)(ws + (10u << 20));       // 10..18MiB
  ushort* attn_b = (ushort*)(ws + (18u << 20));     // 18..26MiB (reuse qkv)

  k_f32_to_bf16<<<dim3((S_LEN * HDIM) / 1024), 256, 0, stream>>>(hidden, x_b,
                                                                 (S_LEN * HDIM) / 4);
  k_transpose_bf16<<<dim3(32, 32), 256, 0, stream>>>(Wq, wt, 2048, 2048);
  k_transpose_bf16<<<dim3(4, 32), 256, 0, stream>>>(Wk, wt + (size_t)2048 * 2048, 2048, 256);
  k_transpose_bf16<<<dim3(4, 32), 256, 0, stream>>>(Wv, wt + (size_t)2304 * 2048, 2048, 256);
  k_gemm_bt<0><<<dim3(16, 40), 256, 0, stream>>>(x_b, wt, qkv, bq, bk, bv, 2048, 2560, 2048);
  k_transpose_bf16<<<dim3(32, 32), 256, 0, stream>>>(Wo, wo_t, 2048, 2048);
  k_rope<<<dim3(S_LEN), 256, 0, stream>>>(qkv, pos_ids, q_r, k_r, v_t, cache_k, cache_v);
  k_attn<<<dim3(512), 256, 0, stream>>>(q_r, k_r, v_t, attn_b);
  k_gemm_bt<1><<<dim3(16, 32), 256, 0, stream>>>(attn_b, wo_t, out, nullptr, nullptr,
                                                 nullptr, 2048, 2048, 2048);
}

// Round 5
// 158.917 us; speedup vs baseline: 1.3981x; 1.0631x over previous
//
#include <hip/hip_runtime.h>
#include <hip/hip_bf16.h>
#include <math.h>

#define S_LEN 2048
#define HDIM  2048
#define N_H   16
#define N_KV  2
#define HD_   128
#define NQKV  2560

typedef __attribute__((ext_vector_type(8))) short bf16x8;
typedef __attribute__((ext_vector_type(4))) float f32x4;
typedef __attribute__((ext_vector_type(16))) float f32x16;

#define GLDS16(gsrc, ldst)                                                      \
  __builtin_amdgcn_global_load_lds(                                             \
      (const __attribute__((address_space(1))) void*)(gsrc),                    \
      (__attribute__((address_space(3))) void*)(ldst), 16, 0, 0)

__device__ __forceinline__ ushort f2b(float x) {
  union { __hip_bfloat16 b; ushort u; } c;
  c.b = __float2bfloat16(x);
  return c.u;
}
__device__ __forceinline__ float b2f(ushort u) {
  union { float f; unsigned v; } c;
  c.v = ((unsigned)u) << 16;
  return c.f;
}
__device__ __forceinline__ uint pk2(float a, float b) {
  return (uint)f2b(a) | ((uint)f2b(b) << 16);
}

// ---------------- f32 -> bf16 elementwise (x conversion) ----------------
__global__ __launch_bounds__(256) void k_f32_to_bf16(const float* __restrict__ src,
                                                     ushort* __restrict__ dst, int n4) {
  int i = blockIdx.x * 256 + threadIdx.x;
  if (i >= n4) return;
  float4 v = ((const float4*)src)[i];
  ushort4 o;
  o.x = f2b(v.x); o.y = f2b(v.y); o.z = f2b(v.z); o.w = f2b(v.w);
  ((ushort4*)dst)[i] = o;
}

// ---------------- f32 [R][C] -> bf16 [C][R] tiled transpose ----------------
__global__ __launch_bounds__(256) void k_transpose_bf16(const float* __restrict__ src,
                                                        ushort* __restrict__ dst,
                                                        int R, int C) {
  __shared__ float t[64][65];
  int c0 = blockIdx.x * 64, r0 = blockIdx.y * 64;
  int tx = threadIdx.x & 63, ty = threadIdx.x >> 6;
#pragma unroll
  for (int i = 0; i < 16; ++i)
    t[i * 4 + ty][tx] = src[(size_t)(r0 + i * 4 + ty) * C + (c0 + tx)];
  __syncthreads();
#pragma unroll
  for (int i = 0; i < 16; ++i)
    dst[(size_t)(c0 + i * 4 + ty) * R + (r0 + tx)] = f2b(t[tx][i * 4 + ty]);
}

// ------- bf16 GEMM 128x128, K-split via blockIdx.z; bf16 partial slices -----
__global__ __launch_bounds__(256) void k_gemm_bt(const ushort* __restrict__ A,
                                                 const ushort* __restrict__ Bt,
                                                 ushort* __restrict__ Cp,
                                                 int M, int N, int Kfull, int Khalf) {
  __shared__ ushort lA[128 * 32];
  __shared__ ushort lB[128 * 32];
  const int tid = threadIdx.x;
  const int w = tid >> 6, lane = tid & 63;
  const int lr = lane & 15, lg = lane >> 4;
  const int bm = blockIdx.x * 128, bn = blockIdx.y * 128;
  const int wm = (w >> 1) * 64, wn = (w & 1) * 64;
  const int kbeg = blockIdx.z * Khalf;
  ushort* Cout = Cp + (size_t)blockIdx.z * M * N;
  f32x4 acc[4][4] = {};

  for (int k0 = kbeg; k0 < kbeg + Khalf; k0 += 32) {
    __syncthreads();
#pragma unroll
    for (int it = 0; it < 2; ++it) {
      const int idx = it * 256 + tid;
      const int row = idx >> 2;
      const int kc = (idx & 3) * 8;
      GLDS16(A + (size_t)(bm + row) * Kfull + k0 + kc, lA + (it * 4 + w) * 512);
      GLDS16(Bt + (size_t)(bn + row) * Kfull + k0 + kc, lB + (it * 4 + w) * 512);
    }
    __syncthreads();
    bf16x8 af[4], bf[4];
#pragma unroll
    for (int i = 0; i < 4; ++i) {
      af[i] = *(const bf16x8*)(lA + (wm + i * 16 + lr) * 32 + lg * 8);
      bf[i] = *(const bf16x8*)(lB + (wn + i * 16 + lr) * 32 + lg * 8);
    }
    __builtin_amdgcn_s_setprio(1);
#pragma unroll
    for (int mi = 0; mi < 4; ++mi)
#pragma unroll
      for (int ni = 0; ni < 4; ++ni)
        acc[mi][ni] =
            __builtin_amdgcn_mfma_f32_16x16x32_bf16(af[mi], bf[ni], acc[mi][ni], 0, 0, 0);
    __builtin_amdgcn_s_setprio(0);
  }

#pragma unroll
  for (int mi = 0; mi < 4; ++mi)
#pragma unroll
    for (int ni = 0; ni < 4; ++ni)
#pragma unroll
      for (int r = 0; r < 4; ++r) {
        const int row = bm + wm + mi * 16 + lg * 4 + r;
        const int col = bn + wn + ni * 16 + lr;
        Cout[(size_t)row * N + col] = f2b(acc[mi][ni][r]);
      }
}

// ------- fused QKV epilogue (partials+bias, bf16 semantics) + RoPE ---------
__global__ __launch_bounds__(256) void k_epirope(const ushort* __restrict__ p0,
                                                 const ushort* __restrict__ p1,
                                                 const float* __restrict__ bq,
                                                 const float* __restrict__ bk,
                                                 const float* __restrict__ bv,
                                                 const int* __restrict__ pos_ids,
                                                 ushort* __restrict__ q_r,
                                                 ushort* __restrict__ k_r,
                                                 ushort* __restrict__ v_t,
                                                 float* __restrict__ cache_k,
                                                 float* __restrict__ cache_v) {
  const int s = blockIdx.x;
  const int t = threadIdx.x;
  __shared__ float row[NQKV];
  const uint* a = (const uint*)(p0 + (size_t)s * NQKV);
  const uint* b = (const uint*)(p1 + (size_t)s * NQKV);
#pragma unroll
  for (int j = 0; j < 5; ++j) {
    const int c2 = t + 256 * j;  // 1280 uint pairs
    const uint u0 = a[c2], u1 = b[c2];
    const int c = 2 * c2;
    const float v0 = b2f((ushort)u0) + b2f((ushort)(u1 & 0xffff));
    const float v1 = b2f((ushort)(u0 >> 16)) + b2f((ushort)(u1 >> 16));
    const float bias0 = (c < 2048) ? bq[c] : (c < 2304 ? bk[c - 2048] : bv[c - 2304]);
    const float bias1 = (c + 1 < 2048) ? bq[c + 1]
                                       : (c + 1 < 2304 ? bk[c + 1 - 2048] : bv[c + 1 - 2304]);
    row[c] = b2f(f2b(b2f(f2b(v0)) + b2f(f2b(bias0))));
    row[c + 1] = b2f(f2b(b2f(f2b(v1)) + b2f(f2b(bias1))));
  }
  __syncthreads();

  const int i = t & 63, g = t >> 6;
  const float SCALE = 0.08838834764831845f;  // 1/sqrt(128)
  const float pos = (float)pos_ids[s];
  const float freq = (float)(1.0 / pow(1000000.0, (double)i / 64.0));
  float sn, cs;
  sincosf(pos * freq, &sn, &cs);

#pragma unroll
  for (int j = 0; j < 4; ++j) {
    const int h = j * 4 + g;
    const float x1 = row[h * 128 + i];
    const float x2 = row[h * 128 + 64 + i];
    const float o1 = x1 * cs - x2 * sn;
    const float o2 = x1 * sn + x2 * cs;
    const size_t qo = ((size_t)h * S_LEN + s) * 128;
    q_r[qo + i] = f2b(o1 * SCALE);
    q_r[qo + 64 + i] = f2b(o2 * SCALE);
  }
  if (g < 2) {
    const int kv = g;
    const float x1 = row[2048 + kv * 128 + i];
    const float x2 = row[2048 + kv * 128 + 64 + i];
    const float o1 = x1 * cs - x2 * sn;
    const float o2 = x1 * sn + x2 * cs;
    const size_t ko = ((size_t)kv * S_LEN + s) * 128;
    k_r[ko + i] = f2b(o1);
    k_r[ko + 64 + i] = f2b(o2);
    const size_t co = ((size_t)s * 2 + kv) * 128;
    cache_k[co + i] = o1;
    cache_k[co + 64 + i] = o2;
  }
  {
    const int kv = t >> 7, d = t & 127;
    const float vval = row[2304 + kv * 128 + d];
    cache_v[((size_t)s * 2 + kv) * 128 + d] = vval;
    v_t[((size_t)kv * 128 + d) * S_LEN + s] = f2b(vval);
  }
}

// ------- out-proj epilogue: add 2 bf16 partial slices, round, f32 out ------
__global__ __launch_bounds__(256) void k_addround(const ushort* __restrict__ p0,
                                                  const ushort* __restrict__ p1,
                                                  float* __restrict__ out, int n2) {
  int i = blockIdx.x * 256 + threadIdx.x;
  if (i >= n2) return;
  const uint a = ((const uint*)p0)[i];
  const uint b = ((const uint*)p1)[i];
  float2 o;
  o.x = b2f(f2b(b2f((ushort)(a & 0xffff)) + b2f((ushort)(b & 0xffff))));
  o.y = b2f(f2b(b2f((ushort)(a >> 16)) + b2f((ushort)(b >> 16))));
  ((float2*)out)[i] = o;
}

// ---------------- flash attention: qt64, KV-split-2, double-buffered -------
// 512 blocks x 4 waves; 32-key tiles; LDS [group][buf][K 8KB | V 8KB] = 64KB.
// Pair decode: blocks i and i+256 share (h,t) with Q = t / 31-t (complement).
__global__ __launch_bounds__(256, 2) void k_attn(const ushort* __restrict__ q_r,
                                                 const ushort* __restrict__ k_r,
                                                 const ushort* __restrict__ v_t,
                                                 ushort* __restrict__ attn_b) {
  __shared__ ushort smem[2][2][8192];  // [group][buf][K:0..4095 | V:4096..8191]
  __shared__ float stats[2][32][2];

  const int bi = blockIdx.x;
  const int h = bi & 15;
  const int tq = (bi >> 4) & 15;
  const int Q = (bi >> 8) ? (31 - tq) : tq;  // qt64 index, complementary pairs
  const int kvh = h >> 3;

  const int tid = threadIdx.x, w = tid >> 6, lane = tid & 63;
  const int g = w >> 1, wq = w & 1, tg = tid & 127;
  const int l31 = lane & 31, hb = lane >> 5;
  const int S_steps = Q + 1;                 // 32-key tiles per group
  const int qmaxw = Q * 64 + wq * 32 + 31;

  // Q fragments (B-operand): lane holds Q[q=l31][hd = f*16 + 8*hb + j]
  bf16x8 qf[8];
  {
    const ushort* qp =
        q_r + ((size_t)(h * S_LEN + Q * 64 + wq * 32 + l31)) * 128 + hb * 8;
#pragma unroll
    for (int f = 0; f < 8; ++f) qf[f] = *(const bf16x8*)(qp + f * 16);
  }

  f32x16 acc[4] = {};  // O^T: [d-group] row=d, col=q
  float m = -INFINITY, l = 0.f;

  // Stage one 32-key tile (K [32][128] XOR-swz; V^T [128][32] add-swz)
#define STAGE(BUF, T32)                                                           \
  do {                                                                            \
    const int kb_ = (T32) * 32;                                                   \
    _Pragma("unroll") for (int i = 0; i < 4; ++i) {                               \
      const int idx = i * 128 + tg;                                               \
      {                                                                           \
        const int key = idx >> 4, sl = idx & 15;                                  \
        GLDS16(k_r + ((size_t)(kvh * S_LEN + kb_ + key)) * 128 +                  \
                   ((sl ^ (key & 7)) * 8),                                        \
               &smem[g][BUF][i * 1024 + wq * 512]);                               \
      }                                                                           \
      {                                                                           \
        const int d = idx >> 2, p = idx & 3;                                      \
        const int gs = (p - (d >> 1)) & 3;                                        \
        GLDS16(v_t + ((size_t)(kvh * HD_ + d)) * S_LEN + kb_ + gs * 8,            \
               &smem[g][BUF][4096 + i * 1024 + wq * 512]);                        \
      }                                                                           \
    }                                                                             \
  } while (0)

  STAGE(0, g);
  int buf = 0;

  for (int s = 0; s < S_steps; ++s) {
    __syncthreads();  // per-wave vmcnt drained before barrier: tile s ready
    if (s + 1 < S_steps) STAGE(buf ^ 1, 2 * (s + 1) + g);
    const int kb = (2 * s + g) * 32;

    if (kb <= qmaxw) {
      const ushort* lK = &smem[g][buf][0];
      const ushort* lV = &smem[g][buf][4096];

      f32x16 p0 = {};
      __builtin_amdgcn_s_setprio(1);
#pragma unroll
      for (int f = 0; f < 8; ++f) {
        const int key = l31;
        const bf16x8 kf8 =
            *(const bf16x8*)(lK + key * 128 + (((2 * f + hb) ^ (key & 7)) * 8));
        p0 = __builtin_amdgcn_mfma_f32_32x32x16_bf16(kf8, qf[f], p0, 0, 0, 0);
      }
      __builtin_amdgcn_s_setprio(0);

      // causal mask + tree max (16 vals/lane)
      const int q = Q * 64 + wq * 32 + l31;
      float sv[16];
#pragma unroll
      for (int r = 0; r < 16; ++r) {
        const int key = kb + (r & 3) + 8 * (r >> 2) + 4 * hb;
        sv[r] = (key <= q) ? p0[r] : -INFINITY;
      }
      float t8[8];
#pragma unroll
      for (int j = 0; j < 8; ++j) t8[j] = fmaxf(sv[j], sv[j + 8]);
#pragma unroll
      for (int st = 4; st >= 1; st >>= 1)
#pragma unroll
        for (int j = 0; j < 4; ++j)
          if (j < st) t8[j] = fmaxf(t8[j], t8[j + st]);
      const float mxw = fmaxf(t8[0], __shfl_xor(t8[0], 32));

      // defer-max (T13)
      if (__any(mxw > m + 8.f)) {
        const float mn = fmaxf(m, mxw);
        const float sc = __expf(m - mn);
#pragma unroll
        for (int g2 = 0; g2 < 4; ++g2)
#pragma unroll
          for (int r = 0; r < 16; ++r) acc[g2][r] *= sc;
        l *= sc;
        m = mn;
      }
#pragma unroll
      for (int r = 0; r < 16; ++r) sv[r] = __expf(sv[r] - m);
      float ts[8];
#pragma unroll
      for (int j = 0; j < 8; ++j) ts[j] = sv[j] + sv[j + 8];
#pragma unroll
      for (int st = 4; st >= 1; st >>= 1)
#pragma unroll
        for (int j = 0; j < 4; ++j)
          if (j < st) ts[j] += ts[j + st];
      l += ts[0];

      // P -> bf16 fragments (cross-half exchange)
      uint pk8[8];
#pragma unroll
      for (int j = 0; j < 8; ++j) pk8[j] = pk2(sv[2 * j], sv[2 * j + 1]);
      union FragU { uint wd[4]; bf16x8 v; };
      FragU frag[2];
#pragma unroll
      for (int c1 = 0; c1 < 2; ++c1) {
        uint mine0, mine1, rcv0, rcv1;
        {
          const uint pa = pk8[0 + 4 * c1];
          const uint pb = pk8[2 + 4 * c1];
          const uint mn_ = hb ? pb : pa;
          const uint xc_ = hb ? pa : pb;
          mine0 = mn_;
          rcv0 = (uint)__shfl_xor((int)xc_, 32);
        }
        {
          const uint pa = pk8[1 + 4 * c1];
          const uint pb = pk8[3 + 4 * c1];
          const uint mn_ = hb ? pb : pa;
          const uint xc_ = hb ? pa : pb;
          mine1 = mn_;
          rcv1 = (uint)__shfl_xor((int)xc_, 32);
        }
        frag[c1].wd[0] = hb ? rcv0 : mine0;
        frag[c1].wd[1] = hb ? rcv1 : mine1;
        frag[c1].wd[2] = hb ? mine0 : rcv0;
        frag[c1].wd[3] = hb ? mine1 : rcv1;
      }

      // PV: acc[g2] += V^T[d-group g2] x P
      __builtin_amdgcn_s_setprio(1);
#pragma unroll
      for (int g2 = 0; g2 < 4; ++g2) {
        const int d = g2 * 32 + l31;
#pragma unroll
        for (int c = 0; c < 2; ++c) {
          const int phys = ((2 * c + hb) + (d >> 1)) & 3;
          const bf16x8 vf = *(const bf16x8*)(lV + d * 32 + phys * 8);
          acc[g2] = __builtin_amdgcn_mfma_f32_32x32x16_bf16(vf, frag[c].v, acc[g2], 0, 0, 0);
        }
      }
      __builtin_amdgcn_s_setprio(0);
    }
    buf ^= 1;
  }
  __syncthreads();  // all compute done before smem reuse for merge

  // -------- merge group1 state into group0, then store --------
  float* mrg = (float*)&smem[0][0][0];   // [wq][128 d][32 q] = 32KB
  float* ldsO = (float*)&smem[1][0][0];  // [wq][32 q][128 d] = 32KB
  if (g == 1) {
    const float lt1 = l + __shfl_xor(l, 32);
#pragma unroll
    for (int g2 = 0; g2 < 4; ++g2)
#pragma unroll
      for (int r = 0; r < 16; ++r) {
        const int d5 = (r & 3) + 8 * (r >> 2) + 4 * hb;
        mrg[wq * 4096 + (g2 * 32 + d5) * 32 + l31] = acc[g2][r];
      }
    if (hb == 0) {
      stats[wq][l31][0] = m;
      stats[wq][l31][1] = lt1;
    }
  }
  __syncthreads();
  if (g == 0) {
    const float m1 = stats[wq][l31][0];
    const float l1 = stats[wq][l31][1];
    const float l0 = l + __shfl_xor(l, 32);
    const float ms = fmaxf(m, m1);
    const float f0 = __expf(m - ms);
    const float f1 = __expf(m1 - ms);
    const float inv = 1.0f / (l0 * f0 + l1 * f1);
#pragma unroll
    for (int g2 = 0; g2 < 4; ++g2)
#pragma unroll
      for (int r = 0; r < 16; ++r) {
        const int d5 = (r & 3) + 8 * (r >> 2) + 4 * hb;
        const float o1v = mrg[wq * 4096 + (g2 * 32 + d5) * 32 + l31];
        const float val = (acc[g2][r] * f0 + o1v * f1) * inv;
        ldsO[wq * 4096 + l31 * 128 + g2 * 32 + (d5 ^ l31)] = val;
      }
#pragma unroll
    for (int pass = 0; pass < 8; ++pass) {
      const int qrow = pass * 4 + (lane >> 4);
      const int d0 = (lane & 15) * 8;
      float v[8];
#pragma unroll
      for (int j = 0; j < 8; ++j)
        v[j] = ldsO[wq * 4096 + qrow * 128 + (((d0 + j) & 31) ^ qrow) + (d0 & 96)];
      uint4 o;
      o.x = pk2(v[0], v[1]); o.y = pk2(v[2], v[3]);
      o.z = pk2(v[4], v[5]); o.w = pk2(v[6], v[7]);
      const size_t qg = (size_t)(Q * 64 + wq * 32 + qrow);
      *(uint4*)(attn_b + qg * HDIM + h * 128 + d0) = o;
    }
  }
#undef STAGE
}

// ---------------- launch ----------------
extern "C" void kernel_launch(void* const* d_in, const int* in_sizes, int n_in,
                              void* d_out, int out_size, void* d_ws, size_t ws_size,
                              hipStream_t stream) {
  const float* hidden = (const float*)d_in[0];
  const int* pos_ids = (const int*)d_in[2];
  const float* Wq = (const float*)d_in[3];
  const float* bq = (const float*)d_in[4];
  const float* Wk = (const float*)d_in[5];
  const float* bk = (const float*)d_in[6];
  const float* Wv = (const float*)d_in[7];
  const float* bv = (const float*)d_in[8];
  const float* Wo = (const float*)d_in[9];

  float* out = (float*)d_out;
  float* cache_k = out + (size_t)S_LEN * HDIM;
  float* cache_v = cache_k + (size_t)S_LEN * N_KV * HD_;

  char* ws = (char*)d_ws;
  // Phase 1: x_b @0 (8M), wt @8M (10M), qkv partials @18M,28.5M (10.5M each)
  // Phase 2: wo_t @0 (over x_b), q_r @8M (over wt), k_r @16M, v_t @17M
  // Phase 3: attn_b @18M (over qkvp0), out partials @26M,34.4M (8.4M each)
  ushort* x_b = (ushort*)(ws);
  ushort* wt = (ushort*)(ws + (8ull << 20));
  ushort* qkvp = (ushort*)(ws + (18ull << 20));   // 2 slices of 2048*2560
  ushort* wo_t = (ushort*)(ws);
  ushort* q_r = (ushort*)(ws + (8ull << 20));
  ushort* k_r = (ushort*)(ws + (16ull << 20));
  ushort* v_t = (ushort*)(ws + (17ull << 20));
  ushort* attn_b = (ushort*)(ws + (18ull << 20));
  ushort* outp = (ushort*)(ws + (26ull << 20));   // 2 slices of 2048*2048

  k_f32_to_bf16<<<dim3((S_LEN * HDIM) / 1024), 256, 0, stream>>>(hidden, x_b,
                                                                 (S_LEN * HDIM) / 4);
  k_transpose_bf16<<<dim3(32, 32), 256, 0, stream>>>(Wq, wt, 2048, 2048);
  k_transpose_bf16<<<dim3(4, 32), 256, 0, stream>>>(Wk, wt + (size_t)2048 * 2048, 2048, 256);
  k_transpose_bf16<<<dim3(4, 32), 256, 0, stream>>>(Wv, wt + (size_t)2304 * 2048, 2048, 256);
  k_gemm_bt<<<dim3(16, 20, 2), 256, 0, stream>>>(x_b, wt, qkvp, 2048, 2560, 2048, 1024);
  k_transpose_bf16<<<dim3(32, 32), 256, 0, stream>>>(Wo, wo_t, 2048, 2048);  // x_b dead
  k_epirope<<<dim3(S_LEN), 256, 0, stream>>>(qkvp, qkvp + (size_t)2048 * 2560, bq, bk, bv,
                                             pos_ids, q_r, k_r, v_t, cache_k, cache_v);
  k_attn<<<dim3(512), 256, 0, stream>>>(q_r, k_r, v_t, attn_b);
  k_gemm_bt<<<dim3(16, 16, 2), 256, 0, stream>>>(attn_b, wo_t, outp, 2048, 2048, 2048, 1024);
  k_addround<<<dim3((2048 * 2048 / 2 + 255) / 256), 256, 0, stream>>>(
      outp, outp + (size_t)2048 * 2048, out, 2048 * 2048 / 2);
}